// Round 3
// baseline (612.703 us; speedup 1.0000x reference)
//
#include <hip/hip_runtime.h>
#include <cstddef>

typedef unsigned short u16;
typedef short short8 __attribute__((ext_vector_type(8)));
typedef float f32x4 __attribute__((ext_vector_type(4)));

// db4 filters (cross-correlation taps, matching lax.conv_general_dilated)
__constant__ float c_dec_lo[8] = {
    -0.010597401785069032f, 0.0328830116668852f, 0.030841381835560764f,
    -0.18703481171888114f, -0.027983769416859854f, 0.6308807679298589f,
    0.7148465705529157f, 0.2303778133088965f};
__constant__ float c_dec_hi[8] = {
    -0.2303778133088965f, 0.7148465705529157f, -0.6308807679298589f,
    -0.027983769416859854f, 0.18703481171888114f, 0.030841381835560764f,
    -0.0328830116668852f, -0.010597401785069032f};
__constant__ float c_rec_lo[8] = {
    0.2303778133088965f, 0.7148465705529157f, 0.6308807679298589f,
    -0.027983769416859854f, -0.18703481171888114f, 0.030841381835560764f,
    0.0328830116668852f, -0.010597401785069032f};
__constant__ float c_rec_hi[8] = {
    -0.010597401785069032f, -0.0328830116668852f, 0.030841381835560764f,
    0.18703481171888114f, -0.027983769416859854f, -0.6308807679298589f,
    0.7148465705529157f, -0.2303778133088965f};

__device__ __forceinline__ float b2f(u16 v) {
    union { unsigned u; float f; } z; z.u = ((unsigned)v) << 16; return z.f;
}
__device__ __forceinline__ u16 f2b(float f) {
    union { float f; unsigned u; } z; z.f = f;
    unsigned r = z.u + 0x7fffu + ((z.u >> 16) & 1u);
    return (u16)(r >> 16);
}
__device__ __forceinline__ unsigned pk2(float a, float b) {
    return (unsigned)f2b(a) | ((unsigned)f2b(b) << 16);
}
__device__ __forceinline__ float gelu_tanh(float x) {
    float u = 0.7978845608028654f * (x + 0.044715f * x * x * x);
    float e = __expf(2.f * u);
    float t = 1.f - 2.f / (e + 1.f);
    return 0.5f * x * (1.f + t);
}

__device__ __forceinline__ float ldel(const float* p, int i) { return p[i]; }
__device__ __forceinline__ float ldel(const u16* p, int i) { return b2f(p[i]); }
__device__ __forceinline__ void ld4(const float* p, int gb, float4& v) {
    v = *(const float4*)(p + gb);
}
__device__ __forceinline__ void ld4(const u16* p, int gb, float4& v) {
    ushort4 u = *(const ushort4*)(p + gb);
    v.x = b2f(u.x); v.y = b2f(u.y); v.z = b2f(u.z); v.w = b2f(u.w);
}

// ---------------- weight pre-fragmentation: fp32 [m][k] -> bf16 MFMA A-frag order
__global__ __launch_bounds__(256) void wconv_kernel(
    const float* __restrict__ s0, const float* __restrict__ s1,
    const float* __restrict__ s2, const float* __restrict__ s3,
    u16* __restrict__ dst)
{
    const float* S[4] = {s0, s1, s2, s3};
    const float* src = S[blockIdx.y];
    u16* d = dst + (size_t)blockIdx.y * 65536;
    int gid = blockIdx.x * 256 + threadIdx.x;  // 0..8191
    int lane = gid & 63;
    int kt = (gid >> 6) & 7;
    int mt = gid >> 9;
    int m = mt * 16 + (lane & 15);
    int k = kt * 32 + (lane >> 4) * 8;
    float4 v0 = *(const float4*)&src[m * 256 + k];
    float4 v1 = *(const float4*)&src[m * 256 + k + 4];
    uint4 o;
    o.x = pk2(v0.x, v0.y); o.y = pk2(v0.z, v0.w);
    o.z = pk2(v1.x, v1.y); o.w = pk2(v1.z, v1.w);
    *(uint4*)&d[(size_t)gid * 8] = o;
}

// ---------------- DWT (fp32 or bf16 in, bf16 out) ----------------
template <typename TI>
__global__ __launch_bounds__(256) void dwt_kernel(
    const TI* __restrict__ X, u16* __restrict__ LO, u16* __restrict__ HI,
    int Lout_shift)
{
    const int Lout = 1 << Lout_shift;
    const int Lin = Lout << 1;
    const int tid = threadIdx.x;
    const int T0 = blockIdx.x << 10;
    const TI* xr = X + ((size_t)blockIdx.y << (Lout_shift + 1));
    const size_t rout = (size_t)blockIdx.y * (size_t)Lout;
    __shared__ float sx[4][520];  // 514 chunks used
    const int g0 = 2 * T0 - 4;
    for (int k = tid; k < 514; k += 256) {
        int gb = g0 + 4 * k;
        float4 v;
        if (gb >= 0 && gb + 4 <= Lin) {
            ld4(xr, gb, v);
        } else {
            v.x = (gb + 0 >= 0 && gb + 0 < Lin) ? ldel(xr, gb + 0) : 0.f;
            v.y = (gb + 1 >= 0 && gb + 1 < Lin) ? ldel(xr, gb + 1) : 0.f;
            v.z = (gb + 2 >= 0 && gb + 2 < Lin) ? ldel(xr, gb + 2) : 0.f;
            v.w = (gb + 3 >= 0 && gb + 3 < Lin) ? ldel(xr, gb + 3) : 0.f;
        }
        sx[0][k] = v.x; sx[1][k] = v.y; sx[2][k] = v.z; sx[3][k] = v.w;
    }
    __syncthreads();
    const int u = tid;  // outputs t = T0+4u..+3; li in [8u+1, 8u+14]
    float xv[14];
#pragma unroll
    for (int n = 0; n < 14; ++n)
        xv[n] = sx[(1 + n) & 3][2 * u + ((1 + n) >> 2)];
    float lo[4], hi[4];
#pragma unroll
    for (int e = 0; e < 4; ++e) {
        float l = 0.f, h = 0.f;
#pragma unroll
        for (int kk = 0; kk < 8; ++kk) {
            float v = xv[2 * e + kk];
            l += c_dec_lo[kk] * v;
            h += c_dec_hi[kk] * v;
        }
        lo[e] = l; hi[e] = h;
    }
    size_t o = rout + T0 + 4 * u;
    uint2 pl; pl.x = pk2(lo[0], lo[1]); pl.y = pk2(lo[2], lo[3]);
    uint2 ph; ph.x = pk2(hi[0], hi[1]); ph.y = pk2(hi[2], hi[3]);
    *(uint2*)&LO[o] = pl;
    *(uint2*)&HI[o] = ph;
}

// ---------------- IDWT (bf16 in, bf16 out) — used for levels 1,2 ----------------
__global__ __launch_bounds__(256) void idwt_kernel(
    const u16* __restrict__ A, const u16* __restrict__ D,
    u16* __restrict__ Y, int Lout_shift)
{
    const int Lout = 1 << Lout_shift;
    const int Lin = Lout >> 1;
    const int tid = threadIdx.x;
    const int T0 = blockIdx.x << 11;
    const size_t rin = (size_t)blockIdx.y * (size_t)Lin;
    const size_t rout = (size_t)blockIdx.y * (size_t)Lout;
    __shared__ float sa[4][264], sd[4][264];  // 258 chunks used
    const int g0 = (T0 >> 1) - 4;
    for (int k = tid; k < 258; k += 256) {
        int gb = g0 + 4 * k;
        float4 va, vd;
        if (gb >= 0 && gb + 4 <= Lin) {
            ld4(A + rin, gb, va);
            ld4(D + rin, gb, vd);
        } else {
            const u16* a = A + rin;
            const u16* d = D + rin;
            va.x = (gb + 0 >= 0 && gb + 0 < Lin) ? b2f(a[gb + 0]) : 0.f;
            va.y = (gb + 1 >= 0 && gb + 1 < Lin) ? b2f(a[gb + 1]) : 0.f;
            va.z = (gb + 2 >= 0 && gb + 2 < Lin) ? b2f(a[gb + 2]) : 0.f;
            va.w = (gb + 3 >= 0 && gb + 3 < Lin) ? b2f(a[gb + 3]) : 0.f;
            vd.x = (gb + 0 >= 0 && gb + 0 < Lin) ? b2f(d[gb + 0]) : 0.f;
            vd.y = (gb + 1 >= 0 && gb + 1 < Lin) ? b2f(d[gb + 1]) : 0.f;
            vd.z = (gb + 2 >= 0 && gb + 2 < Lin) ? b2f(d[gb + 2]) : 0.f;
            vd.w = (gb + 3 >= 0 && gb + 3 < Lin) ? b2f(d[gb + 3]) : 0.f;
        }
        sa[0][k] = va.x; sa[1][k] = va.y; sa[2][k] = va.z; sa[3][k] = va.w;
        sd[0][k] = vd.x; sd[1][k] = vd.y; sd[2][k] = vd.z; sd[3][k] = vd.w;
    }
    __syncthreads();
    const int u = tid;  // outputs t = T0+8u..+7; li in [4u+2, 4u+9]
    float Aa[8], Dd[8];
#pragma unroll
    for (int n = 0; n < 8; ++n) {
        int li = 4 * u + 2 + n;
        Aa[n] = sa[(2 + n) & 3][li >> 2];
        Dd[n] = sd[(2 + n) & 3][li >> 2];
    }
    float o[8];
#pragma unroll
    for (int e = 0; e < 4; ++e) {
        o[2 * e] =
            c_rec_lo[1] * Aa[e + 3] + c_rec_lo[3] * Aa[e + 2] +
            c_rec_lo[5] * Aa[e + 1] + c_rec_lo[7] * Aa[e] +
            c_rec_hi[1] * Dd[e + 3] + c_rec_hi[3] * Dd[e + 2] +
            c_rec_hi[5] * Dd[e + 1] + c_rec_hi[7] * Dd[e];
        o[2 * e + 1] =
            c_rec_lo[0] * Aa[e + 4] + c_rec_lo[2] * Aa[e + 3] +
            c_rec_lo[4] * Aa[e + 2] + c_rec_lo[6] * Aa[e + 1] +
            c_rec_hi[0] * Dd[e + 4] + c_rec_hi[2] * Dd[e + 3] +
            c_rec_hi[4] * Dd[e + 2] + c_rec_hi[6] * Dd[e + 1];
    }
    size_t ob = rout + T0 + 8 * u;
    uint4 pv;
    pv.x = pk2(o[0], o[1]); pv.y = pk2(o[2], o[3]);
    pv.z = pk2(o[4], o[5]); pv.w = pk2(o[6], o[7]);
    *(uint4*)&Y[ob] = pv;
}

// ---------------- fused ResConv1dBlock (bf16 MFMA) ----------------
#define KPAD 264

__device__ __forceinline__ void gemm_phase(
    const u16* __restrict__ Wf, const u16* __restrict__ Bs,
    int lane, int w, int fl, int fq, f32x4 acc[4][4])
{
    const u16* wb = Wf + (size_t)(4 * w) * 4096 + (size_t)lane * 8;
    short8 a[4], an[4];
#pragma unroll
    for (int i = 0; i < 4; ++i)
        a[i] = *(const short8*)(wb + i * 4096);
#pragma unroll
    for (int kt = 0; kt < 8; ++kt) {
        if (kt < 7) {
#pragma unroll
            for (int i = 0; i < 4; ++i)
                an[i] = *(const short8*)(wb + i * 4096 + (kt + 1) * 512);
        }
        short8 bf[4];
#pragma unroll
        for (int nt = 0; nt < 4; ++nt)
            bf[nt] = *(const short8*)&Bs[(nt * 16 + fl) * KPAD + kt * 32 + fq * 8];
#pragma unroll
        for (int i = 0; i < 4; ++i)
#pragma unroll
            for (int nt = 0; nt < 4; ++nt)
                acc[i][nt] = __builtin_amdgcn_mfma_f32_16x16x32_bf16(
                    a[i], bf[nt], acc[i][nt], 0, 0, 0);
#pragma unroll
        for (int i = 0; i < 4; ++i) a[i] = an[i];
    }
}

__device__ __forceinline__ void rb_body(
    const u16* __restrict__ Xg, u16* __restrict__ Outg,
    const u16* __restrict__ W1f, const float* __restrict__ b1,
    const u16* __restrict__ W2f, const float* __restrict__ b2, int L)
{
    __shared__ u16 Xs[64 * KPAD];
    __shared__ u16 Hs[64 * KPAD];
    const int tid = threadIdx.x;
    const int lane = tid & 63;
    const int w = tid >> 6;
    const int fl = lane & 15;
    const int fq = lane >> 4;
    const int n0 = blockIdx.x * 64;
    const size_t bbase = (size_t)blockIdx.y * 256 * (size_t)L;

    // ---- stage X: global [k][n] bf16 -> Xs[n][k] (4x4 register transpose) ----
    {
        const int nq = tid & 15;
        const int kq = tid >> 4;  // 0..15
        const u16* src = Xg + bbase + n0 + 4 * nq;
#pragma unroll
        for (int p = 0; p < 4; ++p) {
            int kb = p * 64 + kq * 4;
            uint2 r0 = *(const uint2*)(src + (size_t)(kb + 0) * L);
            uint2 r1 = *(const uint2*)(src + (size_t)(kb + 1) * L);
            uint2 r2 = *(const uint2*)(src + (size_t)(kb + 2) * L);
            uint2 r3 = *(const uint2*)(src + (size_t)(kb + 3) * L);
#pragma unroll
            for (int j = 0; j < 4; ++j) {
                unsigned e0 = ((j < 2 ? r0.x : r0.y) >> ((j & 1) * 16)) & 0xffffu;
                unsigned e1 = ((j < 2 ? r1.x : r1.y) >> ((j & 1) * 16)) & 0xffffu;
                unsigned e2 = ((j < 2 ? r2.x : r2.y) >> ((j & 1) * 16)) & 0xffffu;
                unsigned e3 = ((j < 2 ? r3.x : r3.y) >> ((j & 1) * 16)) & 0xffffu;
                uint2 o; o.x = e0 | (e1 << 16); o.y = e2 | (e3 << 16);
                *(uint2*)&Xs[(4 * nq + j) * KPAD + kb] = o;
            }
        }
    }
    __syncthreads();

    // ---- GEMM1: H = gelu(W1 @ X + b1) ----
    f32x4 acc[4][4];
#pragma unroll
    for (int i = 0; i < 4; ++i)
#pragma unroll
        for (int nt = 0; nt < 4; ++nt) acc[i][nt] = (f32x4){0.f, 0.f, 0.f, 0.f};
    gemm_phase(W1f, Xs, lane, w, fl, fq, acc);
#pragma unroll
    for (int i = 0; i < 4; ++i) {
        const int m0 = 64 * w + i * 16 + fq * 4;
        float4 bv = *(const float4*)&b1[m0];
#pragma unroll
        for (int nt = 0; nt < 4; ++nt) {
            float v0 = gelu_tanh(acc[i][nt][0] + bv.x);
            float v1 = gelu_tanh(acc[i][nt][1] + bv.y);
            float v2 = gelu_tanh(acc[i][nt][2] + bv.z);
            float v3 = gelu_tanh(acc[i][nt][3] + bv.w);
            uint2 o; o.x = pk2(v0, v1); o.y = pk2(v2, v3);
            *(uint2*)&Hs[(nt * 16 + fl) * KPAD + m0] = o;
        }
    }
    __syncthreads();

    // ---- GEMM2: Out = X0 + W2 @ H + b2 ----
#pragma unroll
    for (int i = 0; i < 4; ++i)
#pragma unroll
        for (int nt = 0; nt < 4; ++nt) acc[i][nt] = (f32x4){0.f, 0.f, 0.f, 0.f};
    gemm_phase(W2f, Hs, lane, w, fl, fq, acc);

    uint2 outv[4][4];
#pragma unroll
    for (int i = 0; i < 4; ++i) {
        const int m0 = 64 * w + i * 16 + fq * 4;
        float4 bv = *(const float4*)&b2[m0];
#pragma unroll
        for (int nt = 0; nt < 4; ++nt) {
            const int n = nt * 16 + fl;
            uint2 x0 = *(const uint2*)&Xs[n * KPAD + m0];
            float v0 = acc[i][nt][0] + bv.x + b2f((u16)(x0.x & 0xffffu));
            float v1 = acc[i][nt][1] + bv.y + b2f((u16)(x0.x >> 16));
            float v2 = acc[i][nt][2] + bv.z + b2f((u16)(x0.y & 0xffffu));
            float v3 = acc[i][nt][3] + bv.w + b2f((u16)(x0.y >> 16));
            outv[i][nt].x = pk2(v0, v1);
            outv[i][nt].y = pk2(v2, v3);
        }
    }
    __syncthreads();  // all waves finished reading Hs
#pragma unroll
    for (int i = 0; i < 4; ++i) {
        const int m0 = 64 * w + i * 16 + fq * 4;
#pragma unroll
        for (int nt = 0; nt < 4; ++nt)
            *(uint2*)&Hs[(nt * 16 + fl) * KPAD + m0] = outv[i][nt];
    }
    __syncthreads();

    // ---- coalesced store: Hs[n][m] -> Out[m][n] ----
    {
        const int n = tid & 63;
        const int mB = (tid >> 6) * 64;
        u16* dst = Outg + bbase + n0 + n;
#pragma unroll
        for (int mi = 0; mi < 16; ++mi) {
            int m = mB + mi * 4;
            uint2 v = *(const uint2*)&Hs[n * KPAD + m];
            dst[(size_t)(m + 0) * L] = (u16)(v.x & 0xffffu);
            dst[(size_t)(m + 1) * L] = (u16)(v.x >> 16);
            dst[(size_t)(m + 2) * L] = (u16)(v.y & 0xffffu);
            dst[(size_t)(m + 3) * L] = (u16)(v.y >> 16);
        }
    }
}

__global__ __launch_bounds__(256, 2) void rb_kernel(
    const u16* __restrict__ Xg, u16* __restrict__ Outg,
    const u16* __restrict__ W1f, const float* __restrict__ b1,
    const u16* __restrict__ W2f, const float* __restrict__ b2, int L)
{
    rb_body(Xg, Outg, W1f, b1, W2f, b2, L);
}

// Two independent res-blocks (same L) in one dispatch: blockIdx.z selects.
__global__ __launch_bounds__(256, 2) void rb_dual_kernel(
    const u16* __restrict__ Xg0, u16* __restrict__ Og0,
    const u16* __restrict__ W1a, const float* __restrict__ b1a,
    const u16* __restrict__ W2a, const float* __restrict__ b2a,
    const u16* __restrict__ Xg1, u16* __restrict__ Og1,
    const u16* __restrict__ W1b, const float* __restrict__ b1b,
    const u16* __restrict__ W2b, const float* __restrict__ b2b, int L)
{
    const u16* Xg; u16* Og; const u16* W1; const float* B1;
    const u16* W2; const float* B2;
    if (blockIdx.z == 0) { Xg = Xg0; Og = Og0; W1 = W1a; B1 = b1a; W2 = W2a; B2 = b2a; }
    else                 { Xg = Xg1; Og = Og1; W1 = W1b; B1 = b1b; W2 = W2b; B2 = b2b; }
    rb_body(Xg, Og, W1, B1, W2, B2, L);
}

// ---------------- fused IDWT level-3 + skip + LayerNorm ----------------
// Per block: 32 output columns x 256 channels of one batch.
// y[c][t] = idwt(A1,D1) at level 8192; out = LN_c(y + x) * g + b  (fp32 out).
// A/D strips (20 elems + halo) staged in LDS (stride 22: worst 2-way conflict
// = free). Values held in registers (16 ch x 2 cols per thread), register-LN
// reduction via shfl_xor(16/32) + 1KB cross-wave stage.
#define SP 22

__global__ __launch_bounds__(256) void iln_kernel(
    const u16* __restrict__ A, const u16* __restrict__ D,
    const float* __restrict__ X, float* __restrict__ O,
    const float* __restrict__ g, const float* __restrict__ be)
{
    __shared__ u16 As[256][SP], Ds[256][SP];
    __shared__ float ps[4][16][4];
    __shared__ float smu[32], srs[32];
    const int tid = threadIdx.x;
    const int lp = tid & 15;   // column pair: cols T+2lp, T+2lp+1
    const int cg = tid >> 4;   // channel group (16 ch)
    const int c0 = cg * 16;
    const int T = blockIdx.x * 32;     // output column base (level 8192)
    const int s0 = (T >> 1) - 2;       // strip base (level 4096), 20 elems, even
    const size_t rinb  = (size_t)blockIdx.y * 256 * 4096;
    const size_t routb = (size_t)blockIdx.y * 256 * 8192;

    // ---- stage A/D strips: thread = channel row, 10 aligned ushort2 loads ----
    {
        const u16* a = A + rinb + (size_t)tid * 4096;
        const u16* d = D + rinb + (size_t)tid * 4096;
#pragma unroll
        for (int j = 0; j < 10; ++j) {
            int e = s0 + 2 * j;
            unsigned va = 0u, vd = 0u;
            if (e >= 0 && e < 4096) {   // e even => e+1 also in range
                va = *(const unsigned*)(a + e);
                vd = *(const unsigned*)(d + e);
            }
            *(unsigned*)&As[tid][2 * j] = va;
            *(unsigned*)&Ds[tid][2 * j] = vd;
        }
    }
    __syncthreads();

    const float rl0 = c_rec_lo[0], rl1 = c_rec_lo[1], rl2 = c_rec_lo[2],
                rl3 = c_rec_lo[3], rl4 = c_rec_lo[4], rl5 = c_rec_lo[5],
                rl6 = c_rec_lo[6], rl7 = c_rec_lo[7];
    const float rh0 = c_rec_hi[0], rh1 = c_rec_hi[1], rh2 = c_rec_hi[2],
                rh3 = c_rec_hi[3], rh4 = c_rec_hi[4], rh5 = c_rec_hi[5],
                rh6 = c_rec_hi[6], rh7 = c_rec_hi[7];

    // ---- per-thread: 16 channels x 2 columns, idwt + skip, accumulate stats ----
    float v0[16], v1[16];
    float s0f = 0.f, s1f = 0.f, q0f = 0.f, q1f = 0.f;
#pragma unroll
    for (int i = 0; i < 16; ++i) {
        const int c = c0 + i;
        float a0 = b2f(As[c][lp + 0]), a1 = b2f(As[c][lp + 1]),
              a2 = b2f(As[c][lp + 2]), a3 = b2f(As[c][lp + 3]),
              a4 = b2f(As[c][lp + 4]);
        float d0 = b2f(Ds[c][lp + 0]), d1 = b2f(Ds[c][lp + 1]),
              d2 = b2f(Ds[c][lp + 2]), d3 = b2f(Ds[c][lp + 3]),
              d4 = b2f(Ds[c][lp + 4]);
        // even col t=T+2lp: taps rec[7],rec[5],rec[3],rec[1] on strip[lp..lp+3]
        float ye = rl7 * a0 + rl5 * a1 + rl3 * a2 + rl1 * a3 +
                   rh7 * d0 + rh5 * d1 + rh3 * d2 + rh1 * d3;
        // odd col t=T+2lp+1: taps rec[6],rec[4],rec[2],rec[0] on strip[lp+1..lp+4]
        float yo = rl6 * a1 + rl4 * a2 + rl2 * a3 + rl0 * a4 +
                   rh6 * d1 + rh4 * d2 + rh2 * d3 + rh0 * d4;
        size_t xa = routb + (size_t)c * 8192 + T + 2 * lp;
        float2 x2 = *(const float2*)&X[xa];
        float va = ye + x2.x;
        float vb = yo + x2.y;
        v0[i] = va; v1[i] = vb;
        s0f += va; q0f += va * va;
        s1f += vb; q1f += vb * vb;
    }
    // intra-wave reduce across the wave's 4 channel groups (lane bits 4..5)
    s0f += __shfl_xor(s0f, 16); q0f += __shfl_xor(q0f, 16);
    s1f += __shfl_xor(s1f, 16); q1f += __shfl_xor(q1f, 16);
    s0f += __shfl_xor(s0f, 32); q0f += __shfl_xor(q0f, 32);
    s1f += __shfl_xor(s1f, 32); q1f += __shfl_xor(q1f, 32);
    const int w = tid >> 6;
    if ((tid & 63) < 16) {
        ps[w][lp][0] = s0f; ps[w][lp][1] = q0f;
        ps[w][lp][2] = s1f; ps[w][lp][3] = q1f;
    }
    __syncthreads();
    if (tid < 16) {
        float S0 = 0.f, Q0 = 0.f, S1 = 0.f, Q1 = 0.f;
#pragma unroll
        for (int i = 0; i < 4; ++i) {
            S0 += ps[i][tid][0]; Q0 += ps[i][tid][1];
            S1 += ps[i][tid][2]; Q1 += ps[i][tid][3];
        }
        float m0 = S0 * (1.f / 256.f), m1 = S1 * (1.f / 256.f);
        smu[2 * tid] = m0;
        smu[2 * tid + 1] = m1;
        srs[2 * tid] = rsqrtf(Q0 * (1.f / 256.f) - m0 * m0 + 1e-5f);
        srs[2 * tid + 1] = rsqrtf(Q1 * (1.f / 256.f) - m1 * m1 + 1e-5f);
    }
    __syncthreads();
    const float mu0 = smu[2 * lp], mu1 = smu[2 * lp + 1];
    const float rs0 = srs[2 * lp], rs1 = srs[2 * lp + 1];
#pragma unroll
    for (int i = 0; i < 16; ++i) {
        const int c = c0 + i;
        size_t oa = routb + (size_t)c * 8192 + T + 2 * lp;
        float gg = g[c], bb = be[c];
        float2 out;
        out.x = (v0[i] - mu0) * rs0 * gg + bb;
        out.y = (v1[i] - mu1) * rs1 * gg + bb;
        *(float2*)&O[oa] = out;
    }
}

extern "C" void kernel_launch(void* const* d_in, const int* in_sizes, int n_in,
                              void* d_out, int out_size, void* d_ws, size_t ws_size,
                              hipStream_t stream) {
    const float* x     = (const float*)d_in[0];
    const float* ab_w1 = (const float*)d_in[1];
    const float* ab_b1 = (const float*)d_in[2];
    const float* ab_w2 = (const float*)d_in[3];
    const float* ab_b2 = (const float*)d_in[4];
    const float* db_w1 = (const float*)d_in[5];
    const float* db_b1 = (const float*)d_in[6];
    const float* db_w2 = (const float*)d_in[7];
    const float* db_b2 = (const float*)d_in[8];
    const float* ln_g  = (const float*)d_in[9];
    const float* ln_b  = (const float*)d_in[10];

    // workspace (bf16): A1,D1 @4096; A2,D2 @2048; A3,D3 @1024; Y @8192; Wf
    u16* A1 = (u16*)d_ws;
    u16* D1 = A1 + (size_t)16 * 256 * 4096;
    u16* A2 = D1 + (size_t)16 * 256 * 4096;
    u16* D2 = A2 + (size_t)16 * 256 * 2048;
    u16* A3 = D2 + (size_t)16 * 256 * 2048;
    u16* D3 = A3 + (size_t)16 * 256 * 1024;
    u16* Yb = D3 + (size_t)16 * 256 * 1024;
    u16* Wf = Yb + (size_t)16 * 256 * 8192;
    u16* Wdb1 = Wf;
    u16* Wdb2 = Wf + 65536;
    u16* Wab1 = Wf + 131072;
    u16* Wab2 = Wf + 196608;

    wconv_kernel<<<dim3(32, 4), 256, 0, stream>>>(db_w1, db_w2, ab_w1, ab_w2, Wf);

    // ---- analysis ----
    dwt_kernel<float><<<dim3(4, 4096), 256, 0, stream>>>(x, A1, D1, 12);   // 8192->4096
    rb_kernel<<<dim3(64, 16), 256, 0, stream>>>(D1, D1, Wdb1, db_b1, Wdb2, db_b2, 4096);
    dwt_kernel<u16><<<dim3(2, 4096), 256, 0, stream>>>(A1, A2, D2, 11);    // 4096->2048
    rb_kernel<<<dim3(32, 16), 256, 0, stream>>>(D2, D2, Wdb1, db_b1, Wdb2, db_b2, 2048);
    dwt_kernel<u16><<<dim3(1, 4096), 256, 0, stream>>>(A2, A3, D3, 10);    // 2048->1024
    // both L=1024 res-blocks (detail-3 and approx-3) in one dispatch
    rb_dual_kernel<<<dim3(16, 16, 2), 256, 0, stream>>>(
        D3, D3, Wdb1, db_b1, Wdb2, db_b2,
        A3, A3, Wab1, ab_b1, Wab2, ab_b2, 1024);

    // ---- synthesis (A2, A1 slots reused as scratch) ----
    idwt_kernel<<<dim3(1, 4096), 256, 0, stream>>>(A3, D3, A2, 11);  // 1024->2048
    idwt_kernel<<<dim3(2, 4096), 256, 0, stream>>>(A2, D2, A1, 12);  // 2048->4096

    // ---- fused idwt level-3 + skip + layer norm -> d_out (fp32) ----
    iln_kernel<<<dim3(256, 16), 256, 0, stream>>>(A1, D1, x, (float*)d_out,
                                                  ln_g, ln_b);
}

// Round 4
// 494.693 us; speedup vs baseline: 1.2386x; 1.2386x over previous
//
#include <hip/hip_runtime.h>
#include <cstddef>

typedef unsigned short u16;
typedef short short8 __attribute__((ext_vector_type(8)));
typedef float f32x4 __attribute__((ext_vector_type(4)));

// db4 filters (cross-correlation taps, matching lax.conv_general_dilated)
__constant__ float c_dec_lo[8] = {
    -0.010597401785069032f, 0.0328830116668852f, 0.030841381835560764f,
    -0.18703481171888114f, -0.027983769416859854f, 0.6308807679298589f,
    0.7148465705529157f, 0.2303778133088965f};
__constant__ float c_dec_hi[8] = {
    -0.2303778133088965f, 0.7148465705529157f, -0.6308807679298589f,
    -0.027983769416859854f, 0.18703481171888114f, 0.030841381835560764f,
    -0.0328830116668852f, -0.010597401785069032f};
__constant__ float c_rec_lo[8] = {
    0.2303778133088965f, 0.7148465705529157f, 0.6308807679298589f,
    -0.027983769416859854f, -0.18703481171888114f, 0.030841381835560764f,
    0.0328830116668852f, -0.010597401785069032f};
__constant__ float c_rec_hi[8] = {
    -0.010597401785069032f, -0.0328830116668852f, 0.030841381835560764f,
    0.18703481171888114f, -0.027983769416859854f, -0.6308807679298589f,
    0.7148465705529157f, -0.2303778133088965f};

__device__ __forceinline__ float b2f(u16 v) {
    union { unsigned u; float f; } z; z.u = ((unsigned)v) << 16; return z.f;
}
__device__ __forceinline__ u16 f2b(float f) {
    union { float f; unsigned u; } z; z.f = f;
    unsigned r = z.u + 0x7fffu + ((z.u >> 16) & 1u);
    return (u16)(r >> 16);
}
__device__ __forceinline__ unsigned pk2(float a, float b) {
    return (unsigned)f2b(a) | ((unsigned)f2b(b) << 16);
}
__device__ __forceinline__ float gelu_tanh(float x) {
    float u = 0.7978845608028654f * (x + 0.044715f * x * x * x);
    float e = __expf(2.f * u);
    float t = 1.f - 2.f / (e + 1.f);
    return 0.5f * x * (1.f + t);
}

// ---------------- weight pre-fragmentation: fp32 [m][k] -> bf16 MFMA A-frag order
__global__ __launch_bounds__(256) void wconv_kernel(
    const float* __restrict__ s0, const float* __restrict__ s1,
    const float* __restrict__ s2, const float* __restrict__ s3,
    u16* __restrict__ dst)
{
    const float* S[4] = {s0, s1, s2, s3};
    const float* src = S[blockIdx.y];
    u16* d = dst + (size_t)blockIdx.y * 65536;
    int gid = blockIdx.x * 256 + threadIdx.x;  // 0..8191
    int lane = gid & 63;
    int kt = (gid >> 6) & 7;
    int mt = gid >> 9;
    int m = mt * 16 + (lane & 15);
    int k = kt * 32 + (lane >> 4) * 8;
    float4 v0 = *(const float4*)&src[m * 256 + k];
    float4 v1 = *(const float4*)&src[m * 256 + k + 4];
    uint4 o;
    o.x = pk2(v0.x, v0.y); o.y = pk2(v0.z, v0.w);
    o.z = pk2(v1.x, v1.y); o.w = pk2(v1.z, v1.w);
    *(uint4*)&d[(size_t)gid * 8] = o;
}

// ---------------- fused 3-level DWT (one block per (b,c) row) ----------------
// x row (8192 fp32) staged in LDS; A-chain kept fp32 in LDS; only D1/D2/D3/A3
// leave to HBM (A1/A2 are pure intermediates). All global I/O contiguous.
// out[t] = sum_k f[k] * in[2t-3+k]   (pad=3, stride 2, verified vs dwt_kernel)
__global__ __launch_bounds__(256) void dwt3_fused_kernel(
    const float* __restrict__ X, u16* __restrict__ D1, u16* __restrict__ D2,
    u16* __restrict__ D3, u16* __restrict__ A3)
{
    __shared__ float xs[8192];   // 32 KB; after level1, [0..2048) reused as A2
    __shared__ float a1[4096];   // 16 KB
    const int tid = threadIdx.x;
    const size_t r = blockIdx.x;           // row = b*256 + c
    const float* xr = X + r * 8192;
#pragma unroll
    for (int i = 0; i < 8; ++i) {
        int idx = (tid + i * 256) * 4;
        *(float4*)&xs[idx] = *(const float4*)&xr[idx];
    }
    __syncthreads();

    // ---- level 1: 8192 -> 4096 (lo -> a1 LDS fp32, hi -> D1 global bf16) ----
    u16* d1r = D1 + r * 4096;
#pragma unroll
    for (int i = 0; i < 16; ++i) {
        int t = tid + i * 256;             // out col 0..4095
        int base = 2 * t - 3;
        float l = 0.f, h = 0.f;
#pragma unroll
        for (int k = 0; k < 8; ++k) {
            int idx = base + k;
            float v = (idx >= 0 && idx < 8192) ? xs[idx] : 0.f;
            l += c_dec_lo[k] * v;
            h += c_dec_hi[k] * v;
        }
        a1[t] = l;
        d1r[t] = f2b(h);
    }
    __syncthreads();

    // ---- level 2: 4096 -> 2048 (lo -> xs[0..2048) as A2, hi -> D2) ----
    u16* d2r = D2 + r * 2048;
#pragma unroll
    for (int i = 0; i < 8; ++i) {
        int t = tid + i * 256;             // 0..2047
        int base = 2 * t - 3;
        float l = 0.f, h = 0.f;
#pragma unroll
        for (int k = 0; k < 8; ++k) {
            int idx = base + k;
            float v = (idx >= 0 && idx < 4096) ? a1[idx] : 0.f;
            l += c_dec_lo[k] * v;
            h += c_dec_hi[k] * v;
        }
        xs[t] = l;
        d2r[t] = f2b(h);
    }
    __syncthreads();

    // ---- level 3: 2048 -> 1024 (lo -> A3, hi -> D3) ----
    u16* d3r = D3 + r * 1024;
    u16* a3r = A3 + r * 1024;
#pragma unroll
    for (int i = 0; i < 4; ++i) {
        int t = tid + i * 256;             // 0..1023
        int base = 2 * t - 3;
        float l = 0.f, h = 0.f;
#pragma unroll
        for (int k = 0; k < 8; ++k) {
            int idx = base + k;
            float v = (idx >= 0 && idx < 2048) ? xs[idx] : 0.f;
            l += c_dec_lo[k] * v;
            h += c_dec_hi[k] * v;
        }
        a3r[t] = f2b(l);
        d3r[t] = f2b(h);
    }
}

// ---------------- fused 3-level IDWT (one block per (b,c) row) ----------------
// Stage A3/D3/D2/D1 rows in LDS (bf16), reconstruct 1024->2048->4096->8192
// with fp32 intermediates in LDS, write Y row once. Formulas verified via
// R3's passing iln kernel:
//  even col 2s:   y = rl7*A[s-2]+rl5*A[s-1]+rl3*A[s]+rl1*A[s+1] + (hi taps on D)
//  odd  col 2s+1: y = rl6*A[s-1]+rl4*A[s]+rl2*A[s+1]+rl0*A[s+2] + (hi taps on D)
__global__ __launch_bounds__(256) void idwt3_fused_kernel(
    const u16* __restrict__ A3, const u16* __restrict__ D3,
    const u16* __restrict__ D2, const u16* __restrict__ D1,
    u16* __restrict__ Y)
{
    __shared__ float fb[6144];   // y2048 [0..2048), y4096 [2048..6144)  24 KB
    __shared__ u16 sb[8192];     // a3 [0,1024) d3 [1024,2048) d2 [2048,4096) d1 [4096,8192)
    const int tid = threadIdx.x;
    const size_t r = blockIdx.x;
    {
        const uint4* a3r = (const uint4*)(A3 + r * 1024);
        const uint4* d3r = (const uint4*)(D3 + r * 1024);
        const uint4* d2r = (const uint4*)(D2 + r * 2048);
        const uint4* d1r = (const uint4*)(D1 + r * 4096);
        uint4* s = (uint4*)sb;
        for (int i = tid; i < 128; i += 256) s[i] = a3r[i];
        for (int i = tid; i < 128; i += 256) s[128 + i] = d3r[i];
        for (int i = tid; i < 256; i += 256) s[256 + i] = d2r[i];
        for (int i = tid; i < 512; i += 256) s[512 + i] = d1r[i];
    }
    __syncthreads();

    const float rl0 = c_rec_lo[0], rl1 = c_rec_lo[1], rl2 = c_rec_lo[2],
                rl3 = c_rec_lo[3], rl4 = c_rec_lo[4], rl5 = c_rec_lo[5],
                rl6 = c_rec_lo[6], rl7 = c_rec_lo[7];
    const float rh0 = c_rec_hi[0], rh1 = c_rec_hi[1], rh2 = c_rec_hi[2],
                rh3 = c_rec_hi[3], rh4 = c_rec_hi[4], rh5 = c_rec_hi[5],
                rh6 = c_rec_hi[6], rh7 = c_rec_hi[7];

    // ---- stage 1: (a3,d3)@1024 -> y2048 (fp32 LDS) ----
#pragma unroll
    for (int i = 0; i < 4; ++i) {
        int s = tid + i * 256;             // pair index: cols 2s, 2s+1
        float a0 = (s >= 2)    ? b2f(sb[s - 2])        : 0.f;
        float a1 = (s >= 1)    ? b2f(sb[s - 1])        : 0.f;
        float a2 = b2f(sb[s]);
        float a3 = (s <= 1022) ? b2f(sb[s + 1])        : 0.f;
        float a4 = (s <= 1021) ? b2f(sb[s + 2])        : 0.f;
        float d0 = (s >= 2)    ? b2f(sb[1024 + s - 2]) : 0.f;
        float d1 = (s >= 1)    ? b2f(sb[1024 + s - 1]) : 0.f;
        float d2 = b2f(sb[1024 + s]);
        float d3 = (s <= 1022) ? b2f(sb[1024 + s + 1]) : 0.f;
        float d4 = (s <= 1021) ? b2f(sb[1024 + s + 2]) : 0.f;
        fb[2 * s]     = rl7 * a0 + rl5 * a1 + rl3 * a2 + rl1 * a3 +
                        rh7 * d0 + rh5 * d1 + rh3 * d2 + rh1 * d3;
        fb[2 * s + 1] = rl6 * a1 + rl4 * a2 + rl2 * a3 + rl0 * a4 +
                        rh6 * d1 + rh4 * d2 + rh2 * d3 + rh0 * d4;
    }
    __syncthreads();

    // ---- stage 2: (y2048, d2)@2048 -> y4096 (fp32 LDS at fb+2048) ----
#pragma unroll
    for (int i = 0; i < 8; ++i) {
        int s = tid + i * 256;
        float a0 = (s >= 2)    ? fb[s - 2]             : 0.f;
        float a1 = (s >= 1)    ? fb[s - 1]             : 0.f;
        float a2 = fb[s];
        float a3 = (s <= 2046) ? fb[s + 1]             : 0.f;
        float a4 = (s <= 2045) ? fb[s + 2]             : 0.f;
        float d0 = (s >= 2)    ? b2f(sb[2048 + s - 2]) : 0.f;
        float d1 = (s >= 1)    ? b2f(sb[2048 + s - 1]) : 0.f;
        float d2 = b2f(sb[2048 + s]);
        float d3 = (s <= 2046) ? b2f(sb[2048 + s + 1]) : 0.f;
        float d4 = (s <= 2045) ? b2f(sb[2048 + s + 2]) : 0.f;
        fb[2048 + 2 * s]     = rl7 * a0 + rl5 * a1 + rl3 * a2 + rl1 * a3 +
                               rh7 * d0 + rh5 * d1 + rh3 * d2 + rh1 * d3;
        fb[2048 + 2 * s + 1] = rl6 * a1 + rl4 * a2 + rl2 * a3 + rl0 * a4 +
                               rh6 * d1 + rh4 * d2 + rh2 * d3 + rh0 * d4;
    }
    __syncthreads();

    // ---- stage 3: (y4096, d1)@4096 -> Y row (bf16 global) ----
    u16* yr = Y + r * 8192;
#pragma unroll
    for (int i = 0; i < 16; ++i) {
        int s = tid + i * 256;
        float a0 = (s >= 2)    ? fb[2048 + s - 2]      : 0.f;
        float a1 = (s >= 1)    ? fb[2048 + s - 1]      : 0.f;
        float a2 = fb[2048 + s];
        float a3 = (s <= 4094) ? fb[2048 + s + 1]      : 0.f;
        float a4 = (s <= 4093) ? fb[2048 + s + 2]      : 0.f;
        float d0 = (s >= 2)    ? b2f(sb[4096 + s - 2]) : 0.f;
        float d1 = (s >= 1)    ? b2f(sb[4096 + s - 1]) : 0.f;
        float d2 = b2f(sb[4096 + s]);
        float d3 = (s <= 4094) ? b2f(sb[4096 + s + 1]) : 0.f;
        float d4 = (s <= 4093) ? b2f(sb[4096 + s + 2]) : 0.f;
        float ye = rl7 * a0 + rl5 * a1 + rl3 * a2 + rl1 * a3 +
                   rh7 * d0 + rh5 * d1 + rh3 * d2 + rh1 * d3;
        float yo = rl6 * a1 + rl4 * a2 + rl2 * a3 + rl0 * a4 +
                   rh6 * d1 + rh4 * d2 + rh2 * d3 + rh0 * d4;
        *(unsigned*)&yr[2 * s] = pk2(ye, yo);
    }
}

// ---------------- fused ResConv1dBlock (bf16 MFMA) ----------------
#define KPAD 264

__device__ __forceinline__ void gemm_phase(
    const u16* __restrict__ Wf, const u16* __restrict__ Bs,
    int lane, int w, int fl, int fq, f32x4 acc[4][4])
{
    const u16* wb = Wf + (size_t)(4 * w) * 4096 + (size_t)lane * 8;
    short8 a[4], an[4];
#pragma unroll
    for (int i = 0; i < 4; ++i)
        a[i] = *(const short8*)(wb + i * 4096);
#pragma unroll
    for (int kt = 0; kt < 8; ++kt) {
        if (kt < 7) {
#pragma unroll
            for (int i = 0; i < 4; ++i)
                an[i] = *(const short8*)(wb + i * 4096 + (kt + 1) * 512);
        }
        short8 bf[4];
#pragma unroll
        for (int nt = 0; nt < 4; ++nt)
            bf[nt] = *(const short8*)&Bs[(nt * 16 + fl) * KPAD + kt * 32 + fq * 8];
#pragma unroll
        for (int i = 0; i < 4; ++i)
#pragma unroll
            for (int nt = 0; nt < 4; ++nt)
                acc[i][nt] = __builtin_amdgcn_mfma_f32_16x16x32_bf16(
                    a[i], bf[nt], acc[i][nt], 0, 0, 0);
#pragma unroll
        for (int i = 0; i < 4; ++i) a[i] = an[i];
    }
}

__device__ __forceinline__ void rb_body(
    const u16* __restrict__ Xg, u16* __restrict__ Outg,
    const u16* __restrict__ W1f, const float* __restrict__ b1,
    const u16* __restrict__ W2f, const float* __restrict__ b2, int L)
{
    __shared__ u16 Xs[64 * KPAD];
    __shared__ u16 Hs[64 * KPAD];
    const int tid = threadIdx.x;
    const int lane = tid & 63;
    const int w = tid >> 6;
    const int fl = lane & 15;
    const int fq = lane >> 4;
    const int n0 = blockIdx.x * 64;
    const size_t bbase = (size_t)blockIdx.y * 256 * (size_t)L;

    // ---- stage X: global [k][n] bf16 -> Xs[n][k] (4x4 register transpose) ----
    {
        const int nq = tid & 15;
        const int kq = tid >> 4;  // 0..15
        const u16* src = Xg + bbase + n0 + 4 * nq;
#pragma unroll
        for (int p = 0; p < 4; ++p) {
            int kb = p * 64 + kq * 4;
            uint2 r0 = *(const uint2*)(src + (size_t)(kb + 0) * L);
            uint2 r1 = *(const uint2*)(src + (size_t)(kb + 1) * L);
            uint2 r2 = *(const uint2*)(src + (size_t)(kb + 2) * L);
            uint2 r3 = *(const uint2*)(src + (size_t)(kb + 3) * L);
#pragma unroll
            for (int j = 0; j < 4; ++j) {
                unsigned e0 = ((j < 2 ? r0.x : r0.y) >> ((j & 1) * 16)) & 0xffffu;
                unsigned e1 = ((j < 2 ? r1.x : r1.y) >> ((j & 1) * 16)) & 0xffffu;
                unsigned e2 = ((j < 2 ? r2.x : r2.y) >> ((j & 1) * 16)) & 0xffffu;
                unsigned e3 = ((j < 2 ? r3.x : r3.y) >> ((j & 1) * 16)) & 0xffffu;
                uint2 o; o.x = e0 | (e1 << 16); o.y = e2 | (e3 << 16);
                *(uint2*)&Xs[(4 * nq + j) * KPAD + kb] = o;
            }
        }
    }
    __syncthreads();

    // ---- GEMM1: H = gelu(W1 @ X + b1) ----
    f32x4 acc[4][4];
#pragma unroll
    for (int i = 0; i < 4; ++i)
#pragma unroll
        for (int nt = 0; nt < 4; ++nt) acc[i][nt] = (f32x4){0.f, 0.f, 0.f, 0.f};
    gemm_phase(W1f, Xs, lane, w, fl, fq, acc);
#pragma unroll
    for (int i = 0; i < 4; ++i) {
        const int m0 = 64 * w + i * 16 + fq * 4;
        float4 bv = *(const float4*)&b1[m0];
#pragma unroll
        for (int nt = 0; nt < 4; ++nt) {
            float v0 = gelu_tanh(acc[i][nt][0] + bv.x);
            float v1 = gelu_tanh(acc[i][nt][1] + bv.y);
            float v2 = gelu_tanh(acc[i][nt][2] + bv.z);
            float v3 = gelu_tanh(acc[i][nt][3] + bv.w);
            uint2 o; o.x = pk2(v0, v1); o.y = pk2(v2, v3);
            *(uint2*)&Hs[(nt * 16 + fl) * KPAD + m0] = o;
        }
    }
    __syncthreads();

    // ---- GEMM2: Out = X0 + W2 @ H + b2 ----
#pragma unroll
    for (int i = 0; i < 4; ++i)
#pragma unroll
        for (int nt = 0; nt < 4; ++nt) acc[i][nt] = (f32x4){0.f, 0.f, 0.f, 0.f};
    gemm_phase(W2f, Hs, lane, w, fl, fq, acc);

    uint2 outv[4][4];
#pragma unroll
    for (int i = 0; i < 4; ++i) {
        const int m0 = 64 * w + i * 16 + fq * 4;
        float4 bv = *(const float4*)&b2[m0];
#pragma unroll
        for (int nt = 0; nt < 4; ++nt) {
            const int n = nt * 16 + fl;
            uint2 x0 = *(const uint2*)&Xs[n * KPAD + m0];
            float v0 = acc[i][nt][0] + bv.x + b2f((u16)(x0.x & 0xffffu));
            float v1 = acc[i][nt][1] + bv.y + b2f((u16)(x0.x >> 16));
            float v2 = acc[i][nt][2] + bv.z + b2f((u16)(x0.y & 0xffffu));
            float v3 = acc[i][nt][3] + bv.w + b2f((u16)(x0.y >> 16));
            outv[i][nt].x = pk2(v0, v1);
            outv[i][nt].y = pk2(v2, v3);
        }
    }
    __syncthreads();  // all waves finished reading Hs
#pragma unroll
    for (int i = 0; i < 4; ++i) {
        const int m0 = 64 * w + i * 16 + fq * 4;
#pragma unroll
        for (int nt = 0; nt < 4; ++nt)
            *(uint2*)&Hs[(nt * 16 + fl) * KPAD + m0] = outv[i][nt];
    }
    __syncthreads();

    // ---- coalesced store: Hs[n][m] -> Out[m][n] ----
    {
        const int n = tid & 63;
        const int mB = (tid >> 6) * 64;
        u16* dst = Outg + bbase + n0 + n;
#pragma unroll
        for (int mi = 0; mi < 16; ++mi) {
            int m = mB + mi * 4;
            uint2 v = *(const uint2*)&Hs[n * KPAD + m];
            dst[(size_t)(m + 0) * L] = (u16)(v.x & 0xffffu);
            dst[(size_t)(m + 1) * L] = (u16)(v.x >> 16);
            dst[(size_t)(m + 2) * L] = (u16)(v.y & 0xffffu);
            dst[(size_t)(m + 3) * L] = (u16)(v.y >> 16);
        }
    }
}

__global__ __launch_bounds__(256, 2) void rb_kernel(
    const u16* __restrict__ Xg, u16* __restrict__ Outg,
    const u16* __restrict__ W1f, const float* __restrict__ b1,
    const u16* __restrict__ W2f, const float* __restrict__ b2, int L)
{
    rb_body(Xg, Outg, W1f, b1, W2f, b2, L);
}

// Two independent res-blocks (same L) in one dispatch: blockIdx.z selects.
__global__ __launch_bounds__(256, 2) void rb_dual_kernel(
    const u16* __restrict__ Xg0, u16* __restrict__ Og0,
    const u16* __restrict__ W1a, const float* __restrict__ b1a,
    const u16* __restrict__ W2a, const float* __restrict__ b2a,
    const u16* __restrict__ Xg1, u16* __restrict__ Og1,
    const u16* __restrict__ W1b, const float* __restrict__ b1b,
    const u16* __restrict__ W2b, const float* __restrict__ b2b, int L)
{
    const u16* Xg; u16* Og; const u16* W1; const float* B1;
    const u16* W2; const float* B2;
    if (blockIdx.z == 0) { Xg = Xg0; Og = Og0; W1 = W1a; B1 = b1a; W2 = W2a; B2 = b2a; }
    else                 { Xg = Xg1; Og = Og1; W1 = W1b; B1 = b1b; W2 = W2b; B2 = b2b; }
    rb_body(Xg, Og, W1, B1, W2, B2, L);
}

// ---------------- LayerNorm over channels: out = LN(y + x) ----------------
// Register-staged one-pass LN (R2-passing version): 32 columns/block,
// 16 channels x 2 columns per thread in VGPRs; shfl_xor(16/32) + 1KB LDS.
__global__ __launch_bounds__(256) void ln_kernel(
    const u16* __restrict__ Yb, const float* __restrict__ X,
    float* __restrict__ O, const float* __restrict__ g, const float* __restrict__ be)
{
    __shared__ float ps[4][16][4];
    __shared__ float smu[32], srs[32];
    const int tid = threadIdx.x;
    const int lp = tid & 15;   // column-pair index: cols 2*lp, 2*lp+1
    const int cg = tid >> 4;   // channel group 0..15 (16 channels each)
    const int c0 = cg * 16;
    const size_t base = (size_t)blockIdx.y * 256 * 8192 +
                        (size_t)blockIdx.x * 32 + 2 * lp;
    float v0[16], v1[16];
    float s0 = 0.f, s1 = 0.f, q0 = 0.f, q1 = 0.f;
#pragma unroll
    for (int i = 0; i < 16; ++i) {
        size_t a = base + (size_t)(c0 + i) * 8192;
        ushort2 y2 = *(const ushort2*)&Yb[a];
        float2 x2 = *(const float2*)&X[a];
        float va = b2f(y2.x) + x2.x;
        float vb = b2f(y2.y) + x2.y;
        v0[i] = va; v1[i] = vb;
        s0 += va; q0 += va * va;
        s1 += vb; q1 += vb * vb;
    }
    s0 += __shfl_xor(s0, 16); q0 += __shfl_xor(q0, 16);
    s1 += __shfl_xor(s1, 16); q1 += __shfl_xor(q1, 16);
    s0 += __shfl_xor(s0, 32); q0 += __shfl_xor(q0, 32);
    s1 += __shfl_xor(s1, 32); q1 += __shfl_xor(q1, 32);
    const int w = tid >> 6;
    if ((tid & 63) < 16) {
        ps[w][lp][0] = s0; ps[w][lp][1] = q0;
        ps[w][lp][2] = s1; ps[w][lp][3] = q1;
    }
    __syncthreads();
    if (tid < 16) {
        float S0 = 0.f, Q0 = 0.f, S1 = 0.f, Q1 = 0.f;
#pragma unroll
        for (int i = 0; i < 4; ++i) {
            S0 += ps[i][tid][0]; Q0 += ps[i][tid][1];
            S1 += ps[i][tid][2]; Q1 += ps[i][tid][3];
        }
        float m0 = S0 * (1.f / 256.f), m1 = S1 * (1.f / 256.f);
        smu[2 * tid] = m0;
        smu[2 * tid + 1] = m1;
        srs[2 * tid] = rsqrtf(Q0 * (1.f / 256.f) - m0 * m0 + 1e-5f);
        srs[2 * tid + 1] = rsqrtf(Q1 * (1.f / 256.f) - m1 * m1 + 1e-5f);
    }
    __syncthreads();
    const float mu0 = smu[2 * lp], mu1 = smu[2 * lp + 1];
    const float rs0 = srs[2 * lp], rs1 = srs[2 * lp + 1];
#pragma unroll
    for (int i = 0; i < 16; ++i) {
        size_t a = base + (size_t)(c0 + i) * 8192;
        float gg = g[c0 + i], bb = be[c0 + i];
        float2 out;
        out.x = (v0[i] - mu0) * rs0 * gg + bb;
        out.y = (v1[i] - mu1) * rs1 * gg + bb;
        *(float2*)&O[a] = out;
    }
}

extern "C" void kernel_launch(void* const* d_in, const int* in_sizes, int n_in,
                              void* d_out, int out_size, void* d_ws, size_t ws_size,
                              hipStream_t stream) {
    const float* x     = (const float*)d_in[0];
    const float* ab_w1 = (const float*)d_in[1];
    const float* ab_b1 = (const float*)d_in[2];
    const float* ab_w2 = (const float*)d_in[3];
    const float* ab_b2 = (const float*)d_in[4];
    const float* db_w1 = (const float*)d_in[5];
    const float* db_b1 = (const float*)d_in[6];
    const float* db_w2 = (const float*)d_in[7];
    const float* db_b2 = (const float*)d_in[8];
    const float* ln_g  = (const float*)d_in[9];
    const float* ln_b  = (const float*)d_in[10];

    // workspace (bf16) — keep R2 slot layout (A1/A2 slots now unused)
    u16* A1 = (u16*)d_ws;
    u16* D1 = A1 + (size_t)16 * 256 * 4096;
    u16* A2 = D1 + (size_t)16 * 256 * 4096;
    u16* D2 = A2 + (size_t)16 * 256 * 2048;
    u16* A3 = D2 + (size_t)16 * 256 * 2048;
    u16* D3 = A3 + (size_t)16 * 256 * 1024;
    u16* Yb = D3 + (size_t)16 * 256 * 1024;
    u16* Wf = Yb + (size_t)16 * 256 * 8192;
    u16* Wdb1 = Wf;
    u16* Wdb2 = Wf + 65536;
    u16* Wab1 = Wf + 131072;
    u16* Wab2 = Wf + 196608;

    wconv_kernel<<<dim3(32, 4), 256, 0, stream>>>(db_w1, db_w2, ab_w1, ab_w2, Wf);

    // ---- analysis: all 3 DWT levels in one dispatch (A1/A2 never hit HBM) ----
    dwt3_fused_kernel<<<4096, 256, 0, stream>>>(x, D1, D2, D3, A3);

    // ---- res blocks ----
    rb_kernel<<<dim3(64, 16), 256, 0, stream>>>(D1, D1, Wdb1, db_b1, Wdb2, db_b2, 4096);
    rb_kernel<<<dim3(32, 16), 256, 0, stream>>>(D2, D2, Wdb1, db_b1, Wdb2, db_b2, 2048);
    rb_dual_kernel<<<dim3(16, 16, 2), 256, 0, stream>>>(
        D3, D3, Wdb1, db_b1, Wdb2, db_b2,
        A3, A3, Wab1, ab_b1, Wab2, ab_b2, 1024);

    // ---- synthesis: all 3 IDWT levels in one dispatch -> Yb ----
    idwt3_fused_kernel<<<4096, 256, 0, stream>>>(A3, D3, D2, D1, Yb);

    // ---- skip + layer norm -> d_out (fp32) ----
    ln_kernel<<<dim3(256, 16), 256, 0, stream>>>(Yb, x, (float*)d_out, ln_g, ln_b);
}

// Round 5
// 463.638 us; speedup vs baseline: 1.3215x; 1.0670x over previous
//
#include <hip/hip_runtime.h>
#include <cstddef>

typedef unsigned short u16;
typedef short short8 __attribute__((ext_vector_type(8)));
typedef float f32x4 __attribute__((ext_vector_type(4)));

// db4 filters (cross-correlation taps, matching lax.conv_general_dilated)
__constant__ float c_dec_lo[8] = {
    -0.010597401785069032f, 0.0328830116668852f, 0.030841381835560764f,
    -0.18703481171888114f, -0.027983769416859854f, 0.6308807679298589f,
    0.7148465705529157f, 0.2303778133088965f};
__constant__ float c_dec_hi[8] = {
    -0.2303778133088965f, 0.7148465705529157f, -0.6308807679298589f,
    -0.027983769416859854f, 0.18703481171888114f, 0.030841381835560764f,
    -0.0328830116668852f, -0.010597401785069032f};
__constant__ float c_rec_lo[8] = {
    0.2303778133088965f, 0.7148465705529157f, 0.6308807679298589f,
    -0.027983769416859854f, -0.18703481171888114f, 0.030841381835560764f,
    0.0328830116668852f, -0.010597401785069032f};
__constant__ float c_rec_hi[8] = {
    -0.010597401785069032f, -0.0328830116668852f, 0.030841381835560764f,
    0.18703481171888114f, -0.027983769416859854f, -0.6308807679298589f,
    0.7148465705529157f, -0.2303778133088965f};

__device__ __forceinline__ float b2f(u16 v) {
    union { unsigned u; float f; } z; z.u = ((unsigned)v) << 16; return z.f;
}
__device__ __forceinline__ u16 f2b(float f) {
    union { float f; unsigned u; } z; z.f = f;
    unsigned r = z.u + 0x7fffu + ((z.u >> 16) & 1u);
    return (u16)(r >> 16);
}
__device__ __forceinline__ unsigned pk2(float a, float b) {
    return (unsigned)f2b(a) | ((unsigned)f2b(b) << 16);
}
__device__ __forceinline__ float gelu_tanh(float x) {
    float u = 0.7978845608028654f * (x + 0.044715f * x * x * x);
    float e = __expf(2.f * u);
    float t = 1.f - 2.f / (e + 1.f);
    return 0.5f * x * (1.f + t);
}

// ---------------- weight pre-fragmentation: fp32 [m][k] -> bf16 MFMA A-frag order
__global__ __launch_bounds__(256) void wconv_kernel(
    const float* __restrict__ s0, const float* __restrict__ s1,
    const float* __restrict__ s2, const float* __restrict__ s3,
    u16* __restrict__ dst)
{
    const float* S[4] = {s0, s1, s2, s3};
    const float* src = S[blockIdx.y];
    u16* d = dst + (size_t)blockIdx.y * 65536;
    int gid = blockIdx.x * 256 + threadIdx.x;  // 0..8191
    int lane = gid & 63;
    int kt = (gid >> 6) & 7;
    int mt = gid >> 9;
    int m = mt * 16 + (lane & 15);
    int k = kt * 32 + (lane >> 4) * 8;
    float4 v0 = *(const float4*)&src[m * 256 + k];
    float4 v1 = *(const float4*)&src[m * 256 + k + 4];
    uint4 o;
    o.x = pk2(v0.x, v0.y); o.y = pk2(v0.z, v0.w);
    o.z = pk2(v1.x, v1.y); o.w = pk2(v1.z, v1.w);
    *(uint4*)&d[(size_t)gid * 8] = o;
}

// ---------------- fused 3-level DWT (one block per (b,c) row) ----------------
// Halo-padded LDS (arr[i] = v[i-4], 4 zeros each side) -> no boundary branches.
// Window reads: 5 aligned float2 per output (8B/lane stride = conflict-free).
// out[t] = sum_k f[k]*in[2t-3+k]; in[2t-3+k] = arr[2t+1+k] -> arr[2t..2t+9].
__global__ __launch_bounds__(256) void dwt3_fused_kernel(
    const float* __restrict__ X, u16* __restrict__ D1, u16* __restrict__ D2,
    u16* __restrict__ D3, u16* __restrict__ A3)
{
    __shared__ __align__(16) float xsh[8200];  // x: [4,8196) valid, halos zero
    __shared__ __align__(16) float a1h[4104];  // a1: [4,4100) valid
    const int tid = threadIdx.x;
    const size_t r = blockIdx.x;               // row = b*256 + c
    const float* xr = X + r * 8192;
#pragma unroll
    for (int i = 0; i < 8; ++i) {
        int j = (tid + i * 256) * 4;
        *(float4*)&xsh[j + 4] = *(const float4*)&xr[j];   // 16B aligned
    }
    if (tid < 4) {
        xsh[tid] = 0.f; xsh[8196 + tid] = 0.f;
        a1h[tid] = 0.f; a1h[4100 + tid] = 0.f;
    }
    __syncthreads();

    // ---- level 1: 8192 -> 4096 (lo -> a1h fp32, hi -> D1 bf16) ----
    u16* d1r = D1 + r * 4096;
#pragma unroll 4
    for (int i = 0; i < 16; ++i) {
        int t = tid + i * 256;
        const float2* p = (const float2*)&xsh[2 * t];
        float2 f0 = p[0], f1 = p[1], f2 = p[2], f3 = p[3], f4 = p[4];
        float w0 = f0.y, w1 = f1.x, w2 = f1.y, w3 = f2.x,
              w4 = f2.y, w5 = f3.x, w6 = f3.y, w7 = f4.x;
        float l = c_dec_lo[0]*w0 + c_dec_lo[1]*w1 + c_dec_lo[2]*w2 + c_dec_lo[3]*w3 +
                  c_dec_lo[4]*w4 + c_dec_lo[5]*w5 + c_dec_lo[6]*w6 + c_dec_lo[7]*w7;
        float h = c_dec_hi[0]*w0 + c_dec_hi[1]*w1 + c_dec_hi[2]*w2 + c_dec_hi[3]*w3 +
                  c_dec_hi[4]*w4 + c_dec_hi[5]*w5 + c_dec_hi[6]*w6 + c_dec_hi[7]*w7;
        a1h[t + 4] = l;
        d1r[t] = f2b(h);
    }
    __syncthreads();

    // ---- level 2: 4096 -> 2048 (lo -> A2 overlay on xsh, hi -> D2) ----
    u16* d2r = D2 + r * 2048;
    if (tid < 4) { xsh[tid] = 0.f; xsh[2052 + tid] = 0.f; }  // A2 halos
#pragma unroll 4
    for (int i = 0; i < 8; ++i) {
        int t = tid + i * 256;
        const float2* p = (const float2*)&a1h[2 * t];
        float2 f0 = p[0], f1 = p[1], f2 = p[2], f3 = p[3], f4 = p[4];
        float w0 = f0.y, w1 = f1.x, w2 = f1.y, w3 = f2.x,
              w4 = f2.y, w5 = f3.x, w6 = f3.y, w7 = f4.x;
        float l = c_dec_lo[0]*w0 + c_dec_lo[1]*w1 + c_dec_lo[2]*w2 + c_dec_lo[3]*w3 +
                  c_dec_lo[4]*w4 + c_dec_lo[5]*w5 + c_dec_lo[6]*w6 + c_dec_lo[7]*w7;
        float h = c_dec_hi[0]*w0 + c_dec_hi[1]*w1 + c_dec_hi[2]*w2 + c_dec_hi[3]*w3 +
                  c_dec_hi[4]*w4 + c_dec_hi[5]*w5 + c_dec_hi[6]*w6 + c_dec_hi[7]*w7;
        xsh[t + 4] = l;
        d2r[t] = f2b(h);
    }
    __syncthreads();

    // ---- level 3: 2048 -> 1024 (lo -> A3, hi -> D3) ----
    u16* d3r = D3 + r * 1024;
    u16* a3r = A3 + r * 1024;
#pragma unroll 4
    for (int i = 0; i < 4; ++i) {
        int t = tid + i * 256;
        const float2* p = (const float2*)&xsh[2 * t];
        float2 f0 = p[0], f1 = p[1], f2 = p[2], f3 = p[3], f4 = p[4];
        float w0 = f0.y, w1 = f1.x, w2 = f1.y, w3 = f2.x,
              w4 = f2.y, w5 = f3.x, w6 = f3.y, w7 = f4.x;
        float l = c_dec_lo[0]*w0 + c_dec_lo[1]*w1 + c_dec_lo[2]*w2 + c_dec_lo[3]*w3 +
                  c_dec_lo[4]*w4 + c_dec_lo[5]*w5 + c_dec_lo[6]*w6 + c_dec_lo[7]*w7;
        float h = c_dec_hi[0]*w0 + c_dec_hi[1]*w1 + c_dec_hi[2]*w2 + c_dec_hi[3]*w3 +
                  c_dec_hi[4]*w4 + c_dec_hi[5]*w5 + c_dec_hi[6]*w6 + c_dec_hi[7]*w7;
        a3r[t] = f2b(l);
        d3r[t] = f2b(h);
    }
}

// ---------------- fused 3-level IDWT (one block per (b,c) row) ----------------
// Halo-padded u16/fp32 LDS buffers (arr[i]=v[i-4]); scalar u16 reads are 2-way
// (free), scalar f32 reads conflict-free; float2 LDS writes; no branches.
// Per pair s: even 2s = rl7*A[s-2]+rl5*A[s-1]+rl3*A[s]+rl1*A[s+1] (+rh on D);
//             odd 2s+1 = rl6*A[s-1]+rl4*A[s]+rl2*A[s+1]+rl0*A[s+2] (+rh on D).
__global__ __launch_bounds__(256) void idwt3_fused_kernel(
    const u16* __restrict__ A3, const u16* __restrict__ D3,
    const u16* __restrict__ D2, const u16* __restrict__ D1,
    u16* __restrict__ Y)
{
    __shared__ __align__(16) u16 a3h[1032], d3h[1032], d2h[2056], d1h[4104];
    __shared__ __align__(16) float y2h[2056], y4h[4104];
    const int tid = threadIdx.x;
    const size_t r = blockIdx.x;

    // ---- stage: global uint4 -> two aligned uint2 LDS writes (halo +4 u16) ----
    {
        const uint4* a3r = (const uint4*)(A3 + r * 1024);   // 128 uint4
        const uint4* d3r = (const uint4*)(D3 + r * 1024);
        const uint4* d2r = (const uint4*)(D2 + r * 2048);   // 256
        const uint4* d1r = (const uint4*)(D1 + r * 4096);   // 512
        for (int i = tid; i < 128; i += 256) {
            uint4 g = a3r[i];
            *(uint2*)&a3h[8 * i + 4] = make_uint2(g.x, g.y);
            *(uint2*)&a3h[8 * i + 8] = make_uint2(g.z, g.w);
            uint4 h = d3r[i];
            *(uint2*)&d3h[8 * i + 4] = make_uint2(h.x, h.y);
            *(uint2*)&d3h[8 * i + 8] = make_uint2(h.z, h.w);
        }
        for (int i = tid; i < 256; i += 256) {
            uint4 g = d2r[i];
            *(uint2*)&d2h[8 * i + 4] = make_uint2(g.x, g.y);
            *(uint2*)&d2h[8 * i + 8] = make_uint2(g.z, g.w);
        }
        for (int i = tid; i < 512; i += 256) {
            uint4 g = d1r[i];
            *(uint2*)&d1h[8 * i + 4] = make_uint2(g.x, g.y);
            *(uint2*)&d1h[8 * i + 8] = make_uint2(g.z, g.w);
        }
        if (tid < 4) {
            a3h[tid] = 0; a3h[1028 + tid] = 0;
            d3h[tid] = 0; d3h[1028 + tid] = 0;
            d2h[tid] = 0; d2h[2052 + tid] = 0;
            d1h[tid] = 0; d1h[4100 + tid] = 0;
            y2h[tid] = 0.f; y2h[2052 + tid] = 0.f;
            y4h[tid] = 0.f; y4h[4100 + tid] = 0.f;
        }
    }
    __syncthreads();

    const float rl0 = c_rec_lo[0], rl1 = c_rec_lo[1], rl2 = c_rec_lo[2],
                rl3 = c_rec_lo[3], rl4 = c_rec_lo[4], rl5 = c_rec_lo[5],
                rl6 = c_rec_lo[6], rl7 = c_rec_lo[7];
    const float rh0 = c_rec_hi[0], rh1 = c_rec_hi[1], rh2 = c_rec_hi[2],
                rh3 = c_rec_hi[3], rh4 = c_rec_hi[4], rh5 = c_rec_hi[5],
                rh6 = c_rec_hi[6], rh7 = c_rec_hi[7];

    // ---- stage 1: (a3,d3)@1024 -> y2h ----
#pragma unroll 4
    for (int i = 0; i < 4; ++i) {
        int s = tid + i * 256;
        float a0 = b2f(a3h[s + 2]), a1 = b2f(a3h[s + 3]), a2 = b2f(a3h[s + 4]),
              a3 = b2f(a3h[s + 5]), a4 = b2f(a3h[s + 6]);
        float d0 = b2f(d3h[s + 2]), d1 = b2f(d3h[s + 3]), d2 = b2f(d3h[s + 4]),
              d3 = b2f(d3h[s + 5]), d4 = b2f(d3h[s + 6]);
        float ye = rl7 * a0 + rl5 * a1 + rl3 * a2 + rl1 * a3 +
                   rh7 * d0 + rh5 * d1 + rh3 * d2 + rh1 * d3;
        float yo = rl6 * a1 + rl4 * a2 + rl2 * a3 + rl0 * a4 +
                   rh6 * d1 + rh4 * d2 + rh2 * d3 + rh0 * d4;
        *(float2*)&y2h[2 * s + 4] = make_float2(ye, yo);
    }
    __syncthreads();

    // ---- stage 2: (y2h, d2)@2048 -> y4h ----
#pragma unroll 4
    for (int i = 0; i < 8; ++i) {
        int s = tid + i * 256;
        float a0 = y2h[s + 2], a1 = y2h[s + 3], a2 = y2h[s + 4],
              a3 = y2h[s + 5], a4 = y2h[s + 6];
        float d0 = b2f(d2h[s + 2]), d1 = b2f(d2h[s + 3]), d2 = b2f(d2h[s + 4]),
              d3 = b2f(d2h[s + 5]), d4 = b2f(d2h[s + 6]);
        float ye = rl7 * a0 + rl5 * a1 + rl3 * a2 + rl1 * a3 +
                   rh7 * d0 + rh5 * d1 + rh3 * d2 + rh1 * d3;
        float yo = rl6 * a1 + rl4 * a2 + rl2 * a3 + rl0 * a4 +
                   rh6 * d1 + rh4 * d2 + rh2 * d3 + rh0 * d4;
        *(float2*)&y4h[2 * s + 4] = make_float2(ye, yo);
    }
    __syncthreads();

    // ---- stage 3: (y4h, d1)@4096 -> Y row (bf16) ----
    u16* yr = Y + r * 8192;
#pragma unroll 4
    for (int i = 0; i < 16; ++i) {
        int s = tid + i * 256;
        float a0 = y4h[s + 2], a1 = y4h[s + 3], a2 = y4h[s + 4],
              a3 = y4h[s + 5], a4 = y4h[s + 6];
        float d0 = b2f(d1h[s + 2]), d1 = b2f(d1h[s + 3]), d2 = b2f(d1h[s + 4]),
              d3 = b2f(d1h[s + 5]), d4 = b2f(d1h[s + 6]);
        float ye = rl7 * a0 + rl5 * a1 + rl3 * a2 + rl1 * a3 +
                   rh7 * d0 + rh5 * d1 + rh3 * d2 + rh1 * d3;
        float yo = rl6 * a1 + rl4 * a2 + rl2 * a3 + rl0 * a4 +
                   rh6 * d1 + rh4 * d2 + rh2 * d3 + rh0 * d4;
        *(unsigned*)&yr[2 * s] = pk2(ye, yo);
    }
}

// ---------------- fused ResConv1dBlock (bf16 MFMA) ----------------
#define KPAD 264

__device__ __forceinline__ void gemm_phase(
    const u16* __restrict__ Wf, const u16* __restrict__ Bs,
    int lane, int w, int fl, int fq, f32x4 acc[4][4])
{
    const u16* wb = Wf + (size_t)(4 * w) * 4096 + (size_t)lane * 8;
    short8 a[4], an[4];
#pragma unroll
    for (int i = 0; i < 4; ++i)
        a[i] = *(const short8*)(wb + i * 4096);
#pragma unroll
    for (int kt = 0; kt < 8; ++kt) {
        if (kt < 7) {
#pragma unroll
            for (int i = 0; i < 4; ++i)
                an[i] = *(const short8*)(wb + i * 4096 + (kt + 1) * 512);
        }
        short8 bf[4];
#pragma unroll
        for (int nt = 0; nt < 4; ++nt)
            bf[nt] = *(const short8*)&Bs[(nt * 16 + fl) * KPAD + kt * 32 + fq * 8];
#pragma unroll
        for (int i = 0; i < 4; ++i)
#pragma unroll
            for (int nt = 0; nt < 4; ++nt)
                acc[i][nt] = __builtin_amdgcn_mfma_f32_16x16x32_bf16(
                    a[i], bf[nt], acc[i][nt], 0, 0, 0);
#pragma unroll
        for (int i = 0; i < 4; ++i) a[i] = an[i];
    }
}

__device__ __forceinline__ void rb_body(
    const u16* __restrict__ Xg, u16* __restrict__ Outg,
    const u16* __restrict__ W1f, const float* __restrict__ b1,
    const u16* __restrict__ W2f, const float* __restrict__ b2, int L)
{
    __shared__ u16 Xs[64 * KPAD];
    __shared__ u16 Hs[64 * KPAD];
    const int tid = threadIdx.x;
    const int lane = tid & 63;
    const int w = tid >> 6;
    const int fl = lane & 15;
    const int fq = lane >> 4;
    const int n0 = blockIdx.x * 64;
    const size_t bbase = (size_t)blockIdx.y * 256 * (size_t)L;

    // ---- stage X: global [k][n] bf16 -> Xs[n][k] (4x4 register transpose) ----
    {
        const int nq = tid & 15;
        const int kq = tid >> 4;  // 0..15
        const u16* src = Xg + bbase + n0 + 4 * nq;
#pragma unroll
        for (int p = 0; p < 4; ++p) {
            int kb = p * 64 + kq * 4;
            uint2 r0 = *(const uint2*)(src + (size_t)(kb + 0) * L);
            uint2 r1 = *(const uint2*)(src + (size_t)(kb + 1) * L);
            uint2 r2 = *(const uint2*)(src + (size_t)(kb + 2) * L);
            uint2 r3 = *(const uint2*)(src + (size_t)(kb + 3) * L);
#pragma unroll
            for (int j = 0; j < 4; ++j) {
                unsigned e0 = ((j < 2 ? r0.x : r0.y) >> ((j & 1) * 16)) & 0xffffu;
                unsigned e1 = ((j < 2 ? r1.x : r1.y) >> ((j & 1) * 16)) & 0xffffu;
                unsigned e2 = ((j < 2 ? r2.x : r2.y) >> ((j & 1) * 16)) & 0xffffu;
                unsigned e3 = ((j < 2 ? r3.x : r3.y) >> ((j & 1) * 16)) & 0xffffu;
                uint2 o; o.x = e0 | (e1 << 16); o.y = e2 | (e3 << 16);
                *(uint2*)&Xs[(4 * nq + j) * KPAD + kb] = o;
            }
        }
    }
    __syncthreads();

    // ---- GEMM1: H = gelu(W1 @ X + b1) ----
    f32x4 acc[4][4];
#pragma unroll
    for (int i = 0; i < 4; ++i)
#pragma unroll
        for (int nt = 0; nt < 4; ++nt) acc[i][nt] = (f32x4){0.f, 0.f, 0.f, 0.f};
    gemm_phase(W1f, Xs, lane, w, fl, fq, acc);
#pragma unroll
    for (int i = 0; i < 4; ++i) {
        const int m0 = 64 * w + i * 16 + fq * 4;
        float4 bv = *(const float4*)&b1[m0];
#pragma unroll
        for (int nt = 0; nt < 4; ++nt) {
            float v0 = gelu_tanh(acc[i][nt][0] + bv.x);
            float v1 = gelu_tanh(acc[i][nt][1] + bv.y);
            float v2 = gelu_tanh(acc[i][nt][2] + bv.z);
            float v3 = gelu_tanh(acc[i][nt][3] + bv.w);
            uint2 o; o.x = pk2(v0, v1); o.y = pk2(v2, v3);
            *(uint2*)&Hs[(nt * 16 + fl) * KPAD + m0] = o;
        }
    }
    __syncthreads();

    // ---- GEMM2: Out = X0 + W2 @ H + b2 ----
#pragma unroll
    for (int i = 0; i < 4; ++i)
#pragma unroll
        for (int nt = 0; nt < 4; ++nt) acc[i][nt] = (f32x4){0.f, 0.f, 0.f, 0.f};
    gemm_phase(W2f, Hs, lane, w, fl, fq, acc);

    uint2 outv[4][4];
#pragma unroll
    for (int i = 0; i < 4; ++i) {
        const int m0 = 64 * w + i * 16 + fq * 4;
        float4 bv = *(const float4*)&b2[m0];
#pragma unroll
        for (int nt = 0; nt < 4; ++nt) {
            const int n = nt * 16 + fl;
            uint2 x0 = *(const uint2*)&Xs[n * KPAD + m0];
            float v0 = acc[i][nt][0] + bv.x + b2f((u16)(x0.x & 0xffffu));
            float v1 = acc[i][nt][1] + bv.y + b2f((u16)(x0.x >> 16));
            float v2 = acc[i][nt][2] + bv.z + b2f((u16)(x0.y & 0xffffu));
            float v3 = acc[i][nt][3] + bv.w + b2f((u16)(x0.y >> 16));
            outv[i][nt].x = pk2(v0, v1);
            outv[i][nt].y = pk2(v2, v3);
        }
    }
    __syncthreads();  // all waves finished reading Hs
#pragma unroll
    for (int i = 0; i < 4; ++i) {
        const int m0 = 64 * w + i * 16 + fq * 4;
#pragma unroll
        for (int nt = 0; nt < 4; ++nt)
            *(uint2*)&Hs[(nt * 16 + fl) * KPAD + m0] = outv[i][nt];
    }
    __syncthreads();

    // ---- coalesced store: Hs[n][m] -> Out[m][n] ----
    {
        const int n = tid & 63;
        const int mB = (tid >> 6) * 64;
        u16* dst = Outg + bbase + n0 + n;
#pragma unroll
        for (int mi = 0; mi < 16; ++mi) {
            int m = mB + mi * 4;
            uint2 v = *(const uint2*)&Hs[n * KPAD + m];
            dst[(size_t)(m + 0) * L] = (u16)(v.x & 0xffffu);
            dst[(size_t)(m + 1) * L] = (u16)(v.x >> 16);
            dst[(size_t)(m + 2) * L] = (u16)(v.y & 0xffffu);
            dst[(size_t)(m + 3) * L] = (u16)(v.y >> 16);
        }
    }
}

__global__ __launch_bounds__(256, 2) void rb_kernel(
    const u16* __restrict__ Xg, u16* __restrict__ Outg,
    const u16* __restrict__ W1f, const float* __restrict__ b1,
    const u16* __restrict__ W2f, const float* __restrict__ b2, int L)
{
    rb_body(Xg, Outg, W1f, b1, W2f, b2, L);
}

// Two independent res-blocks (same L) in one dispatch: blockIdx.z selects.
__global__ __launch_bounds__(256, 2) void rb_dual_kernel(
    const u16* __restrict__ Xg0, u16* __restrict__ Og0,
    const u16* __restrict__ W1a, const float* __restrict__ b1a,
    const u16* __restrict__ W2a, const float* __restrict__ b2a,
    const u16* __restrict__ Xg1, u16* __restrict__ Og1,
    const u16* __restrict__ W1b, const float* __restrict__ b1b,
    const u16* __restrict__ W2b, const float* __restrict__ b2b, int L)
{
    const u16* Xg; u16* Og; const u16* W1; const float* B1;
    const u16* W2; const float* B2;
    if (blockIdx.z == 0) { Xg = Xg0; Og = Og0; W1 = W1a; B1 = b1a; W2 = W2a; B2 = b2a; }
    else                 { Xg = Xg1; Og = Og1; W1 = W1b; B1 = b1b; W2 = W2b; B2 = b2b; }
    rb_body(Xg, Og, W1, B1, W2, B2, L);
}

// ---------------- LayerNorm over channels: out = LN(y + x) ----------------
__global__ __launch_bounds__(256) void ln_kernel(
    const u16* __restrict__ Yb, const float* __restrict__ X,
    float* __restrict__ O, const float* __restrict__ g, const float* __restrict__ be)
{
    __shared__ float ps[4][16][4];
    __shared__ float smu[32], srs[32];
    const int tid = threadIdx.x;
    const int lp = tid & 15;   // column-pair index: cols 2*lp, 2*lp+1
    const int cg = tid >> 4;   // channel group 0..15 (16 channels each)
    const int c0 = cg * 16;
    const size_t base = (size_t)blockIdx.y * 256 * 8192 +
                        (size_t)blockIdx.x * 32 + 2 * lp;
    float v0[16], v1[16];
    float s0 = 0.f, s1 = 0.f, q0 = 0.f, q1 = 0.f;
#pragma unroll
    for (int i = 0; i < 16; ++i) {
        size_t a = base + (size_t)(c0 + i) * 8192;
        ushort2 y2 = *(const ushort2*)&Yb[a];
        float2 x2 = *(const float2*)&X[a];
        float va = b2f(y2.x) + x2.x;
        float vb = b2f(y2.y) + x2.y;
        v0[i] = va; v1[i] = vb;
        s0 += va; q0 += va * va;
        s1 += vb; q1 += vb * vb;
    }
    s0 += __shfl_xor(s0, 16); q0 += __shfl_xor(q0, 16);
    s1 += __shfl_xor(s1, 16); q1 += __shfl_xor(q1, 16);
    s0 += __shfl_xor(s0, 32); q0 += __shfl_xor(q0, 32);
    s1 += __shfl_xor(s1, 32); q1 += __shfl_xor(q1, 32);
    const int w = tid >> 6;
    if ((tid & 63) < 16) {
        ps[w][lp][0] = s0; ps[w][lp][1] = q0;
        ps[w][lp][2] = s1; ps[w][lp][3] = q1;
    }
    __syncthreads();
    if (tid < 16) {
        float S0 = 0.f, Q0 = 0.f, S1 = 0.f, Q1 = 0.f;
#pragma unroll
        for (int i = 0; i < 4; ++i) {
            S0 += ps[i][tid][0]; Q0 += ps[i][tid][1];
            S1 += ps[i][tid][2]; Q1 += ps[i][tid][3];
        }
        float m0 = S0 * (1.f / 256.f), m1 = S1 * (1.f / 256.f);
        smu[2 * tid] = m0;
        smu[2 * tid + 1] = m1;
        srs[2 * tid] = rsqrtf(Q0 * (1.f / 256.f) - m0 * m0 + 1e-5f);
        srs[2 * tid + 1] = rsqrtf(Q1 * (1.f / 256.f) - m1 * m1 + 1e-5f);
    }
    __syncthreads();
    const float mu0 = smu[2 * lp], mu1 = smu[2 * lp + 1];
    const float rs0 = srs[2 * lp], rs1 = srs[2 * lp + 1];
#pragma unroll
    for (int i = 0; i < 16; ++i) {
        size_t a = base + (size_t)(c0 + i) * 8192;
        float gg = g[c0 + i], bb = be[c0 + i];
        float2 out;
        out.x = (v0[i] - mu0) * rs0 * gg + bb;
        out.y = (v1[i] - mu1) * rs1 * gg + bb;
        *(float2*)&O[a] = out;
    }
}

extern "C" void kernel_launch(void* const* d_in, const int* in_sizes, int n_in,
                              void* d_out, int out_size, void* d_ws, size_t ws_size,
                              hipStream_t stream) {
    const float* x     = (const float*)d_in[0];
    const float* ab_w1 = (const float*)d_in[1];
    const float* ab_b1 = (const float*)d_in[2];
    const float* ab_w2 = (const float*)d_in[3];
    const float* ab_b2 = (const float*)d_in[4];
    const float* db_w1 = (const float*)d_in[5];
    const float* db_b1 = (const float*)d_in[6];
    const float* db_w2 = (const float*)d_in[7];
    const float* db_b2 = (const float*)d_in[8];
    const float* ln_g  = (const float*)d_in[9];
    const float* ln_b  = (const float*)d_in[10];

    // workspace (bf16) — keep slot layout (A1/A2 slots unused)
    u16* A1 = (u16*)d_ws;
    u16* D1 = A1 + (size_t)16 * 256 * 4096;
    u16* A2 = D1 + (size_t)16 * 256 * 4096;
    u16* D2 = A2 + (size_t)16 * 256 * 2048;
    u16* A3 = D2 + (size_t)16 * 256 * 2048;
    u16* D3 = A3 + (size_t)16 * 256 * 1024;
    u16* Yb = D3 + (size_t)16 * 256 * 1024;
    u16* Wf = Yb + (size_t)16 * 256 * 8192;
    u16* Wdb1 = Wf;
    u16* Wdb2 = Wf + 65536;
    u16* Wab1 = Wf + 131072;
    u16* Wab2 = Wf + 196608;

    wconv_kernel<<<dim3(32, 4), 256, 0, stream>>>(db_w1, db_w2, ab_w1, ab_w2, Wf);

    // ---- analysis: all 3 DWT levels in one dispatch (A1/A2 never hit HBM) ----
    dwt3_fused_kernel<<<4096, 256, 0, stream>>>(x, D1, D2, D3, A3);

    // ---- res blocks ----
    rb_kernel<<<dim3(64, 16), 256, 0, stream>>>(D1, D1, Wdb1, db_b1, Wdb2, db_b2, 4096);
    rb_kernel<<<dim3(32, 16), 256, 0, stream>>>(D2, D2, Wdb1, db_b1, Wdb2, db_b2, 2048);
    rb_dual_kernel<<<dim3(16, 16, 2), 256, 0, stream>>>(
        D3, D3, Wdb1, db_b1, Wdb2, db_b2,
        A3, A3, Wab1, ab_b1, Wab2, ab_b2, 1024);

    // ---- synthesis: all 3 IDWT levels in one dispatch -> Yb ----
    idwt3_fused_kernel<<<4096, 256, 0, stream>>>(A3, D3, D2, D1, Yb);

    // ---- skip + layer norm -> d_out (fp32) ----
    ln_kernel<<<dim3(256, 16), 256, 0, stream>>>(Yb, x, (float*)d_out, ln_g, ln_b);
}

// Round 7
// 397.736 us; speedup vs baseline: 1.5405x; 1.1657x over previous
//
#include <hip/hip_runtime.h>
#include <cstddef>

typedef unsigned short u16;
typedef short short8 __attribute__((ext_vector_type(8)));
typedef float f32x4 __attribute__((ext_vector_type(4)));

// db4 filters (cross-correlation taps, matching lax.conv_general_dilated)
__constant__ float c_dec_lo[8] = {
    -0.010597401785069032f, 0.0328830116668852f, 0.030841381835560764f,
    -0.18703481171888114f, -0.027983769416859854f, 0.6308807679298589f,
    0.7148465705529157f, 0.2303778133088965f};
__constant__ float c_dec_hi[8] = {
    -0.2303778133088965f, 0.7148465705529157f, -0.6308807679298589f,
    -0.027983769416859854f, 0.18703481171888114f, 0.030841381835560764f,
    -0.0328830116668852f, -0.010597401785069032f};
__constant__ float c_rec_lo[8] = {
    0.2303778133088965f, 0.7148465705529157f, 0.6308807679298589f,
    -0.027983769416859854f, -0.18703481171888114f, 0.030841381835560764f,
    0.0328830116668852f, -0.010597401785069032f};
__constant__ float c_rec_hi[8] = {
    -0.010597401785069032f, -0.0328830116668852f, 0.030841381835560764f,
    0.18703481171888114f, -0.027983769416859854f, -0.6308807679298589f,
    0.7148465705529157f, -0.2303778133088965f};

__device__ __forceinline__ float b2f(u16 v) {
    union { unsigned u; float f; } z; z.u = ((unsigned)v) << 16; return z.f;
}
__device__ __forceinline__ float bl(unsigned u) { return b2f((u16)(u & 0xffffu)); }
__device__ __forceinline__ float bh(unsigned u) { return b2f((u16)(u >> 16)); }
__device__ __forceinline__ u16 f2b(float f) {
    union { float f; unsigned u; } z; z.f = f;
    unsigned r = z.u + 0x7fffu + ((z.u >> 16) & 1u);
    return (u16)(r >> 16);
}
__device__ __forceinline__ unsigned pk2(float a, float b) {
    return (unsigned)f2b(a) | ((unsigned)f2b(b) << 16);
}
__device__ __forceinline__ float gelu_tanh(float x) {
    float u = 0.7978845608028654f * (x + 0.044715f * x * x * x);
    float e = __expf(2.f * u);
    float t = 1.f - 2.f / (e + 1.f);
    return 0.5f * x * (1.f + t);
}

// ---------------- weight pre-fragmentation: fp32 [m][k] -> bf16 MFMA A-frag order
__global__ __launch_bounds__(256) void wconv_kernel(
    const float* __restrict__ s0, const float* __restrict__ s1,
    const float* __restrict__ s2, const float* __restrict__ s3,
    u16* __restrict__ dst)
{
    const float* S[4] = {s0, s1, s2, s3};
    const float* src = S[blockIdx.y];
    u16* d = dst + (size_t)blockIdx.y * 65536;
    int gid = blockIdx.x * 256 + threadIdx.x;  // 0..8191
    int lane = gid & 63;
    int kt = (gid >> 6) & 7;
    int mt = gid >> 9;
    int m = mt * 16 + (lane & 15);
    int k = kt * 32 + (lane >> 4) * 8;
    float4 v0 = *(const float4*)&src[m * 256 + k];
    float4 v1 = *(const float4*)&src[m * 256 + k + 4];
    uint4 o;
    o.x = pk2(v0.x, v0.y); o.y = pk2(v0.z, v0.w);
    o.z = pk2(v1.x, v1.y); o.w = pk2(v1.z, v1.w);
    *(uint4*)&d[(size_t)gid * 8] = o;
}

// ---------------- fused 3-level DWT (one block per (b,c) row) ----------------
// Halo-padded LDS (arr[i]=v[i-4]); PAIR of outputs per iteration: 3x
// ds_read_b128 cover both windows; paired bf16 stores (4B). out[t] uses
// in[2t-3..2t+4] = arr[2t+1..2t+8].
__global__ __launch_bounds__(256) void dwt3_fused_kernel(
    const float* __restrict__ X, u16* __restrict__ D1, u16* __restrict__ D2,
    u16* __restrict__ D3, u16* __restrict__ A3)
{
    __shared__ __align__(16) float xsh[8200];  // x at [4,8196); later A2 at [4,2052)
    __shared__ __align__(16) float a1h[4104];  // a1 at [4,4100)
    const int tid = threadIdx.x;
    const size_t r = blockIdx.x;               // row = b*256 + c
    const float* xr = X + r * 8192;
#pragma unroll
    for (int i = 0; i < 8; ++i) {
        int j = (tid + i * 256) * 4;
        *(float4*)&xsh[j + 4] = *(const float4*)&xr[j];
    }
    if (tid < 4) {
        xsh[tid] = 0.f; xsh[8196 + tid] = 0.f;
        a1h[tid] = 0.f; a1h[4100 + tid] = 0.f;
    }
    __syncthreads();

    // ---- level 1: 8192 -> 4096 ----
    u16* d1r = D1 + r * 4096;
#pragma unroll
    for (int i = 0; i < 8; ++i) {
        int t0 = 2 * (tid + i * 256);          // even, 0..4094
        const float4* p = (const float4*)&xsh[2 * t0];
        float4 f = p[0], g = p[1], h = p[2];   // xsh[2t0 .. 2t0+11]
        float l0 = c_dec_lo[0]*f.y + c_dec_lo[1]*f.z + c_dec_lo[2]*f.w + c_dec_lo[3]*g.x
                 + c_dec_lo[4]*g.y + c_dec_lo[5]*g.z + c_dec_lo[6]*g.w + c_dec_lo[7]*h.x;
        float h0 = c_dec_hi[0]*f.y + c_dec_hi[1]*f.z + c_dec_hi[2]*f.w + c_dec_hi[3]*g.x
                 + c_dec_hi[4]*g.y + c_dec_hi[5]*g.z + c_dec_hi[6]*g.w + c_dec_hi[7]*h.x;
        float l1 = c_dec_lo[0]*f.w + c_dec_lo[1]*g.x + c_dec_lo[2]*g.y + c_dec_lo[3]*g.z
                 + c_dec_lo[4]*g.w + c_dec_lo[5]*h.x + c_dec_lo[6]*h.y + c_dec_lo[7]*h.z;
        float h1 = c_dec_hi[0]*f.w + c_dec_hi[1]*g.x + c_dec_hi[2]*g.y + c_dec_hi[3]*g.z
                 + c_dec_hi[4]*g.w + c_dec_hi[5]*h.x + c_dec_hi[6]*h.y + c_dec_hi[7]*h.z;
        *(float2*)&a1h[t0 + 4] = make_float2(l0, l1);
        *(unsigned*)&d1r[t0] = pk2(h0, h1);
    }
    __syncthreads();

    // ---- level 2: 4096 -> 2048 (lo -> A2 overlay on xsh) ----
    u16* d2r = D2 + r * 2048;
    if (tid < 4) xsh[2052 + tid] = 0.f;        // A2 upper halo (lower already 0)
#pragma unroll
    for (int i = 0; i < 4; ++i) {
        int t0 = 2 * (tid + i * 256);          // 0..2046
        const float4* p = (const float4*)&a1h[2 * t0];
        float4 f = p[0], g = p[1], h = p[2];
        float l0 = c_dec_lo[0]*f.y + c_dec_lo[1]*f.z + c_dec_lo[2]*f.w + c_dec_lo[3]*g.x
                 + c_dec_lo[4]*g.y + c_dec_lo[5]*g.z + c_dec_lo[6]*g.w + c_dec_lo[7]*h.x;
        float h0 = c_dec_hi[0]*f.y + c_dec_hi[1]*f.z + c_dec_hi[2]*f.w + c_dec_hi[3]*g.x
                 + c_dec_hi[4]*g.y + c_dec_hi[5]*g.z + c_dec_hi[6]*g.w + c_dec_hi[7]*h.x;
        float l1 = c_dec_lo[0]*f.w + c_dec_lo[1]*g.x + c_dec_lo[2]*g.y + c_dec_lo[3]*g.z
                 + c_dec_lo[4]*g.w + c_dec_lo[5]*h.x + c_dec_lo[6]*h.y + c_dec_lo[7]*h.z;
        float h1 = c_dec_hi[0]*f.w + c_dec_hi[1]*g.x + c_dec_hi[2]*g.y + c_dec_hi[3]*g.z
                 + c_dec_hi[4]*g.w + c_dec_hi[5]*h.x + c_dec_hi[6]*h.y + c_dec_hi[7]*h.z;
        *(float2*)&xsh[t0 + 4] = make_float2(l0, l1);
        *(unsigned*)&d2r[t0] = pk2(h0, h1);
    }
    __syncthreads();

    // ---- level 3: 2048 -> 1024 ----
    u16* d3r = D3 + r * 1024;
    u16* a3r = A3 + r * 1024;
#pragma unroll
    for (int i = 0; i < 2; ++i) {
        int t0 = 2 * (tid + i * 256);          // 0..1022
        const float4* p = (const float4*)&xsh[2 * t0];
        float4 f = p[0], g = p[1], h = p[2];
        float l0 = c_dec_lo[0]*f.y + c_dec_lo[1]*f.z + c_dec_lo[2]*f.w + c_dec_lo[3]*g.x
                 + c_dec_lo[4]*g.y + c_dec_lo[5]*g.z + c_dec_lo[6]*g.w + c_dec_lo[7]*h.x;
        float h0 = c_dec_hi[0]*f.y + c_dec_hi[1]*f.z + c_dec_hi[2]*f.w + c_dec_hi[3]*g.x
                 + c_dec_hi[4]*g.y + c_dec_hi[5]*g.z + c_dec_hi[6]*g.w + c_dec_hi[7]*h.x;
        float l1 = c_dec_lo[0]*f.w + c_dec_lo[1]*g.x + c_dec_lo[2]*g.y + c_dec_lo[3]*g.z
                 + c_dec_lo[4]*g.w + c_dec_lo[5]*h.x + c_dec_lo[6]*h.y + c_dec_lo[7]*h.z;
        float h1 = c_dec_hi[0]*f.w + c_dec_hi[1]*g.x + c_dec_hi[2]*g.y + c_dec_hi[3]*g.z
                 + c_dec_hi[4]*g.w + c_dec_hi[5]*h.x + c_dec_hi[6]*h.y + c_dec_hi[7]*h.z;
        *(unsigned*)&a3r[t0] = pk2(l0, l1);
        *(unsigned*)&d3r[t0] = pk2(h0, h1);
    }
}

// ---------------- fused 3-level IDWT (one block per (b,c) row) ----------------
// u16 halo 8 (arr[i]=v[i-8], aligned b128 staging); f32 halo 4.
// TWO pairs per iteration: overlapping windows -> 3 packed reads per array.
// even 2s: rl7*A[s-2]+rl5*A[s-1]+rl3*A[s]+rl1*A[s+1] (+rh taps on D)
// odd 2s+1: rl6*A[s-1]+rl4*A[s]+rl2*A[s+1]+rl0*A[s+2] (+rh taps on D)
__global__ __launch_bounds__(256) void idwt3_fused_kernel(
    const u16* __restrict__ A3, const u16* __restrict__ D3,
    const u16* __restrict__ D2, const u16* __restrict__ D1,
    u16* __restrict__ Y)
{
    __shared__ __align__(16) u16 a3h[1040], d3h[1040], d2h[2064], d1h[4112];
    __shared__ __align__(16) float y2h[2056], y4h[4104];
    const int tid = threadIdx.x;
    const size_t r = blockIdx.x;

    {
        const uint4* a3r = (const uint4*)(A3 + r * 1024);   // 128 uint4
        const uint4* d3r = (const uint4*)(D3 + r * 1024);
        const uint4* d2r = (const uint4*)(D2 + r * 2048);   // 256
        const uint4* d1r = (const uint4*)(D1 + r * 4096);   // 512
        if (tid < 128) {
            *(uint4*)&a3h[8 * tid + 8] = a3r[tid];
        } else {
            int j = tid - 128;
            *(uint4*)&d3h[8 * j + 8] = d3r[j];
        }
        *(uint4*)&d2h[8 * tid + 8] = d2r[tid];
        *(uint4*)&d1h[8 * tid + 8] = d1r[tid];
        *(uint4*)&d1h[8 * (tid + 256) + 8] = d1r[tid + 256];
        if (tid < 8) {
            a3h[tid] = 0; a3h[1032 + tid] = 0;
            d3h[tid] = 0; d3h[1032 + tid] = 0;
            d2h[tid] = 0; d2h[2056 + tid] = 0;
            d1h[tid] = 0; d1h[4104 + tid] = 0;
        }
        if (tid < 4) {
            y2h[tid] = 0.f; y2h[2052 + tid] = 0.f;
            y4h[tid] = 0.f; y4h[4100 + tid] = 0.f;
        }
    }
    __syncthreads();

    const float rl0 = c_rec_lo[0], rl1 = c_rec_lo[1], rl2 = c_rec_lo[2],
                rl3 = c_rec_lo[3], rl4 = c_rec_lo[4], rl5 = c_rec_lo[5],
                rl6 = c_rec_lo[6], rl7 = c_rec_lo[7];
    const float rh0 = c_rec_hi[0], rh1 = c_rec_hi[1], rh2 = c_rec_hi[2],
                rh3 = c_rec_hi[3], rh4 = c_rec_hi[4], rh5 = c_rec_hi[5],
                rh6 = c_rec_hi[6], rh7 = c_rec_hi[7];

    // ---- stage 1: (a3,d3)@1024 -> y2h ----
#pragma unroll
    for (int i = 0; i < 2; ++i) {
        int s = 2 * (tid + i * 256);           // even, 0..1022
        unsigned ua0 = *(const unsigned*)&a3h[s + 6];
        unsigned ua1 = *(const unsigned*)&a3h[s + 8];
        unsigned ua2 = *(const unsigned*)&a3h[s + 10];
        unsigned ud0 = *(const unsigned*)&d3h[s + 6];
        unsigned ud1 = *(const unsigned*)&d3h[s + 8];
        unsigned ud2 = *(const unsigned*)&d3h[s + 10];
        float am2 = bl(ua0), am1 = bh(ua0), a0 = bl(ua1), a1 = bh(ua1),
              a2 = bl(ua2), a3 = bh(ua2);
        float dm2 = bl(ud0), dm1 = bh(ud0), d0 = bl(ud1), d1 = bh(ud1),
              d2 = bl(ud2), d3 = bh(ud2);
        float4 o;
        o.x = rl7*am2 + rl5*am1 + rl3*a0 + rl1*a1 + rh7*dm2 + rh5*dm1 + rh3*d0 + rh1*d1;
        o.y = rl6*am1 + rl4*a0 + rl2*a1 + rl0*a2 + rh6*dm1 + rh4*d0 + rh2*d1 + rh0*d2;
        o.z = rl7*am1 + rl5*a0 + rl3*a1 + rl1*a2 + rh7*dm1 + rh5*d0 + rh3*d1 + rh1*d2;
        o.w = rl6*a0 + rl4*a1 + rl2*a2 + rl0*a3 + rh6*d0 + rh4*d1 + rh2*d2 + rh0*d3;
        *(float4*)&y2h[2 * s + 4] = o;
    }
    __syncthreads();

    // ---- stage 2: (y2h, d2)@2048 -> y4h ----
#pragma unroll
    for (int i = 0; i < 4; ++i) {
        int s = 2 * (tid + i * 256);           // 0..2046
        const float2* p = (const float2*)&y2h[s + 2];
        float2 fa = p[0], fb = p[1], fc = p[2];
        float am2 = fa.x, am1 = fa.y, a0 = fb.x, a1 = fb.y, a2 = fc.x, a3 = fc.y;
        unsigned ud0 = *(const unsigned*)&d2h[s + 6];
        unsigned ud1 = *(const unsigned*)&d2h[s + 8];
        unsigned ud2 = *(const unsigned*)&d2h[s + 10];
        float dm2 = bl(ud0), dm1 = bh(ud0), d0 = bl(ud1), d1 = bh(ud1),
              d2 = bl(ud2), d3 = bh(ud2);
        float4 o;
        o.x = rl7*am2 + rl5*am1 + rl3*a0 + rl1*a1 + rh7*dm2 + rh5*dm1 + rh3*d0 + rh1*d1;
        o.y = rl6*am1 + rl4*a0 + rl2*a1 + rl0*a2 + rh6*dm1 + rh4*d0 + rh2*d1 + rh0*d2;
        o.z = rl7*am1 + rl5*a0 + rl3*a1 + rl1*a2 + rh7*dm1 + rh5*d0 + rh3*d1 + rh1*d2;
        o.w = rl6*a0 + rl4*a1 + rl2*a2 + rl0*a3 + rh6*d0 + rh4*d1 + rh2*d2 + rh0*d3;
        *(float4*)&y4h[2 * s + 4] = o;
    }
    __syncthreads();

    // ---- stage 3: (y4h, d1)@4096 -> Y row ----
    u16* yr = Y + r * 8192;
#pragma unroll
    for (int i = 0; i < 8; ++i) {
        int s = 2 * (tid + i * 256);           // 0..4094
        const float2* p = (const float2*)&y4h[s + 2];
        float2 fa = p[0], fb = p[1], fc = p[2];
        float am2 = fa.x, am1 = fa.y, a0 = fb.x, a1 = fb.y, a2 = fc.x, a3 = fc.y;
        unsigned ud0 = *(const unsigned*)&d1h[s + 6];
        unsigned ud1 = *(const unsigned*)&d1h[s + 8];
        unsigned ud2 = *(const unsigned*)&d1h[s + 10];
        float dm2 = bl(ud0), dm1 = bh(ud0), d0 = bl(ud1), d1 = bh(ud1),
              d2 = bl(ud2), d3 = bh(ud2);
        float ye0 = rl7*am2 + rl5*am1 + rl3*a0 + rl1*a1 + rh7*dm2 + rh5*dm1 + rh3*d0 + rh1*d1;
        float yo0 = rl6*am1 + rl4*a0 + rl2*a1 + rl0*a2 + rh6*dm1 + rh4*d0 + rh2*d1 + rh0*d2;
        float ye1 = rl7*am1 + rl5*a0 + rl3*a1 + rl1*a2 + rh7*dm1 + rh5*d0 + rh3*d1 + rh1*d2;
        float yo1 = rl6*a0 + rl4*a1 + rl2*a2 + rl0*a3 + rh6*d0 + rh4*d1 + rh2*d2 + rh0*d3;
        uint2 o; o.x = pk2(ye0, yo0); o.y = pk2(ye1, yo1);
        *(uint2*)&yr[2 * s] = o;
    }
}

// ---------------- fused ResConv1dBlock (bf16 MFMA) ----------------
#define KPAD 264

__device__ __forceinline__ void gemm_phase(
    const u16* __restrict__ Wf, const u16* __restrict__ Bs,
    int lane, int w, int fl, int fq, f32x4 acc[4][4])
{
    const u16* wb = Wf + (size_t)(4 * w) * 4096 + (size_t)lane * 8;
    short8 a[4], an[4];
#pragma unroll
    for (int i = 0; i < 4; ++i)
        a[i] = *(const short8*)(wb + i * 4096);
#pragma unroll
    for (int kt = 0; kt < 8; ++kt) {
        if (kt < 7) {
#pragma unroll
            for (int i = 0; i < 4; ++i)
                an[i] = *(const short8*)(wb + i * 4096 + (kt + 1) * 512);
        }
        short8 bf[4];
#pragma unroll
        for (int nt = 0; nt < 4; ++nt)
            bf[nt] = *(const short8*)&Bs[(nt * 16 + fl) * KPAD + kt * 32 + fq * 8];
#pragma unroll
        for (int i = 0; i < 4; ++i)
#pragma unroll
            for (int nt = 0; nt < 4; ++nt)
                acc[i][nt] = __builtin_amdgcn_mfma_f32_16x16x32_bf16(
                    a[i], bf[nt], acc[i][nt], 0, 0, 0);
#pragma unroll
        for (int i = 0; i < 4; ++i) a[i] = an[i];
    }
}

__device__ __forceinline__ void rb_body(
    const u16* __restrict__ Xg, u16* __restrict__ Outg,
    const u16* __restrict__ W1f, const float* __restrict__ b1,
    const u16* __restrict__ W2f, const float* __restrict__ b2,
    int L, int n0, int batch)
{
    __shared__ u16 Xs[64 * KPAD];
    __shared__ u16 Hs[64 * KPAD];
    const int tid = threadIdx.x;
    const int lane = tid & 63;
    const int w = tid >> 6;
    const int fl = lane & 15;
    const int fq = lane >> 4;
    const size_t bbase = (size_t)batch * 256 * (size_t)L;

    // ---- stage X: global [k][n] bf16 -> Xs[n][k] (4x4 register transpose) ----
    {
        const int nq = tid & 15;
        const int kq = tid >> 4;  // 0..15
        const u16* src = Xg + bbase + n0 + 4 * nq;
#pragma unroll
        for (int p = 0; p < 4; ++p) {
            int kb = p * 64 + kq * 4;
            uint2 r0 = *(const uint2*)(src + (size_t)(kb + 0) * L);
            uint2 r1 = *(const uint2*)(src + (size_t)(kb + 1) * L);
            uint2 r2 = *(const uint2*)(src + (size_t)(kb + 2) * L);
            uint2 r3 = *(const uint2*)(src + (size_t)(kb + 3) * L);
#pragma unroll
            for (int j = 0; j < 4; ++j) {
                unsigned e0 = ((j < 2 ? r0.x : r0.y) >> ((j & 1) * 16)) & 0xffffu;
                unsigned e1 = ((j < 2 ? r1.x : r1.y) >> ((j & 1) * 16)) & 0xffffu;
                unsigned e2 = ((j < 2 ? r2.x : r2.y) >> ((j & 1) * 16)) & 0xffffu;
                unsigned e3 = ((j < 2 ? r3.x : r3.y) >> ((j & 1) * 16)) & 0xffffu;
                uint2 o; o.x = e0 | (e1 << 16); o.y = e2 | (e3 << 16);
                *(uint2*)&Xs[(4 * nq + j) * KPAD + kb] = o;
            }
        }
    }
    __syncthreads();

    // ---- GEMM1: H = gelu(W1 @ X + b1) ----
    f32x4 acc[4][4];
#pragma unroll
    for (int i = 0; i < 4; ++i)
#pragma unroll
        for (int nt = 0; nt < 4; ++nt) acc[i][nt] = (f32x4){0.f, 0.f, 0.f, 0.f};
    gemm_phase(W1f, Xs, lane, w, fl, fq, acc);
#pragma unroll
    for (int i = 0; i < 4; ++i) {
        const int m0 = 64 * w + i * 16 + fq * 4;
        float4 bv = *(const float4*)&b1[m0];
#pragma unroll
        for (int nt = 0; nt < 4; ++nt) {
            float v0 = gelu_tanh(acc[i][nt][0] + bv.x);
            float v1 = gelu_tanh(acc[i][nt][1] + bv.y);
            float v2 = gelu_tanh(acc[i][nt][2] + bv.z);
            float v3 = gelu_tanh(acc[i][nt][3] + bv.w);
            uint2 o; o.x = pk2(v0, v1); o.y = pk2(v2, v3);
            *(uint2*)&Hs[(nt * 16 + fl) * KPAD + m0] = o;
        }
    }
    __syncthreads();

    // ---- GEMM2: Out = X0 + W2 @ H + b2 ----
#pragma unroll
    for (int i = 0; i < 4; ++i)
#pragma unroll
        for (int nt = 0; nt < 4; ++nt) acc[i][nt] = (f32x4){0.f, 0.f, 0.f, 0.f};
    gemm_phase(W2f, Hs, lane, w, fl, fq, acc);

    uint2 outv[4][4];
#pragma unroll
    for (int i = 0; i < 4; ++i) {
        const int m0 = 64 * w + i * 16 + fq * 4;
        float4 bv = *(const float4*)&b2[m0];
#pragma unroll
        for (int nt = 0; nt < 4; ++nt) {
            const int n = nt * 16 + fl;
            uint2 x0 = *(const uint2*)&Xs[n * KPAD + m0];
            float v0 = acc[i][nt][0] + bv.x + b2f((u16)(x0.x & 0xffffu));
            float v1 = acc[i][nt][1] + bv.y + b2f((u16)(x0.x >> 16));
            float v2 = acc[i][nt][2] + bv.z + b2f((u16)(x0.y & 0xffffu));
            float v3 = acc[i][nt][3] + bv.w + b2f((u16)(x0.y >> 16));
            outv[i][nt].x = pk2(v0, v1);
            outv[i][nt].y = pk2(v2, v3);
        }
    }
    __syncthreads();  // all waves finished reading Hs
#pragma unroll
    for (int i = 0; i < 4; ++i) {
        const int m0 = 64 * w + i * 16 + fq * 4;
#pragma unroll
        for (int nt = 0; nt < 4; ++nt)
            *(uint2*)&Hs[(nt * 16 + fl) * KPAD + m0] = outv[i][nt];
    }
    __syncthreads();

    // ---- coalesced store: Hs[n][m] -> Out[m][n] ----
    {
        const int n = tid & 63;
        const int mB = (tid >> 6) * 64;
        u16* dst = Outg + bbase + n0 + n;
#pragma unroll
        for (int mi = 0; mi < 16; ++mi) {
            int m = mB + mi * 4;
            uint2 v = *(const uint2*)&Hs[n * KPAD + m];
            dst[(size_t)(m + 0) * L] = (u16)(v.x & 0xffffu);
            dst[(size_t)(m + 1) * L] = (u16)(v.x >> 16);
            dst[(size_t)(m + 2) * L] = (u16)(v.y & 0xffffu);
            dst[(size_t)(m + 3) * L] = (u16)(v.y >> 16);
        }
    }
}

// All four res-blocks in ONE dispatch (grid 2048):
//   [0,1024):    D1, L=4096 (64 col-blocks x 16 batches)
//   [1024,1536): D2, L=2048 (32 x 16)
//   [1536,1792): D3, L=1024 (16 x 16)
//   [1792,2048): A3, L=1024 (16 x 16, ab weights)
__global__ __launch_bounds__(256, 2) void rb_all_kernel(
    u16* __restrict__ D1, u16* __restrict__ D2, u16* __restrict__ D3,
    u16* __restrict__ A3,
    const u16* __restrict__ Wdb1, const float* __restrict__ db_b1,
    const u16* __restrict__ Wdb2, const float* __restrict__ db_b2,
    const u16* __restrict__ Wab1, const float* __restrict__ ab_b1,
    const u16* __restrict__ Wab2, const float* __restrict__ ab_b2)
{
    const int bx = blockIdx.x;
    u16* Xg; const u16* W1; const float* B1; const u16* W2; const float* B2;
    int L, n0, batch;
    if (bx < 1024) {
        L = 4096; n0 = (bx & 63) * 64; batch = bx >> 6;
        Xg = D1; W1 = Wdb1; B1 = db_b1; W2 = Wdb2; B2 = db_b2;
    } else if (bx < 1536) {
        int lo = bx - 1024;
        L = 2048; n0 = (lo & 31) * 64; batch = lo >> 5;
        Xg = D2; W1 = Wdb1; B1 = db_b1; W2 = Wdb2; B2 = db_b2;
    } else if (bx < 1792) {
        int lo = bx - 1536;
        L = 1024; n0 = (lo & 15) * 64; batch = lo >> 4;
        Xg = D3; W1 = Wdb1; B1 = db_b1; W2 = Wdb2; B2 = db_b2;
    } else {
        int lo = bx - 1792;
        L = 1024; n0 = (lo & 15) * 64; batch = lo >> 4;
        Xg = A3; W1 = Wab1; B1 = ab_b1; W2 = Wab2; B2 = ab_b2;
    }
    rb_body(Xg, Xg, W1, B1, W2, B2, L, n0, batch);
}

// ---------------- LayerNorm over channels: out = LN(y + x) ----------------
// 64 cols/block, 4 cols x 16 channels per thread (ushort4/float4 loads).
__global__ __launch_bounds__(256) void ln_kernel(
    const u16* __restrict__ Yb, const float* __restrict__ X,
    float* __restrict__ O, const float* __restrict__ g, const float* __restrict__ be)
{
    __shared__ float ps[4][16][8];
    __shared__ float smu[64], srs[64];
    const int tid = threadIdx.x;
    const int lp = tid & 15;   // column quad: cols 4*lp .. 4*lp+3
    const int cg = tid >> 4;   // channel group 0..15 (16 channels each)
    const int c0 = cg * 16;
    const size_t base = (size_t)blockIdx.y * 256 * 8192 +
                        (size_t)blockIdx.x * 64 + 4 * lp;
    float v0[16], v1[16], v2[16], v3[16];
    float s0 = 0.f, s1 = 0.f, s2 = 0.f, s3 = 0.f;
    float q0 = 0.f, q1 = 0.f, q2 = 0.f, q3 = 0.f;
#pragma unroll
    for (int i = 0; i < 16; ++i) {
        size_t a = base + (size_t)(c0 + i) * 8192;
        ushort4 y4 = *(const ushort4*)&Yb[a];
        float4 x4 = *(const float4*)&X[a];
        float va = b2f(y4.x) + x4.x;
        float vb = b2f(y4.y) + x4.y;
        float vc = b2f(y4.z) + x4.z;
        float vd = b2f(y4.w) + x4.w;
        v0[i] = va; v1[i] = vb; v2[i] = vc; v3[i] = vd;
        s0 += va; q0 += va * va;
        s1 += vb; q1 += vb * vb;
        s2 += vc; q2 += vc * vc;
        s3 += vd; q3 += vd * vd;
    }
    s0 += __shfl_xor(s0, 16); q0 += __shfl_xor(q0, 16);
    s1 += __shfl_xor(s1, 16); q1 += __shfl_xor(q1, 16);
    s2 += __shfl_xor(s2, 16); q2 += __shfl_xor(q2, 16);
    s3 += __shfl_xor(s3, 16); q3 += __shfl_xor(q3, 16);
    s0 += __shfl_xor(s0, 32); q0 += __shfl_xor(q0, 32);
    s1 += __shfl_xor(s1, 32); q1 += __shfl_xor(q1, 32);
    s2 += __shfl_xor(s2, 32); q2 += __shfl_xor(q2, 32);
    s3 += __shfl_xor(s3, 32); q3 += __shfl_xor(q3, 32);
    const int w = tid >> 6;
    if ((tid & 63) < 16) {
        ps[w][lp][0] = s0; ps[w][lp][1] = q0;
        ps[w][lp][2] = s1; ps[w][lp][3] = q1;
        ps[w][lp][4] = s2; ps[w][lp][5] = q2;
        ps[w][lp][6] = s3; ps[w][lp][7] = q3;
    }
    __syncthreads();
    if (tid < 16) {
#pragma unroll
        for (int j = 0; j < 4; ++j) {
            float S = 0.f, Q = 0.f;
#pragma unroll
            for (int i = 0; i < 4; ++i) {
                S += ps[i][tid][2 * j];
                Q += ps[i][tid][2 * j + 1];
            }
            float m = S * (1.f / 256.f);
            smu[4 * tid + j] = m;
            srs[4 * tid + j] = rsqrtf(Q * (1.f / 256.f) - m * m + 1e-5f);
        }
    }
    __syncthreads();
    const float mu0 = smu[4 * lp + 0], mu1 = smu[4 * lp + 1],
                mu2 = smu[4 * lp + 2], mu3 = smu[4 * lp + 3];
    const float rs0 = srs[4 * lp + 0], rs1 = srs[4 * lp + 1],
                rs2 = srs[4 * lp + 2], rs3 = srs[4 * lp + 3];
#pragma unroll
    for (int i = 0; i < 16; ++i) {
        size_t a = base + (size_t)(c0 + i) * 8192;
        float gg = g[c0 + i], bb = be[c0 + i];
        float4 out;
        out.x = (v0[i] - mu0) * rs0 * gg + bb;
        out.y = (v1[i] - mu1) * rs1 * gg + bb;
        out.z = (v2[i] - mu2) * rs2 * gg + bb;
        out.w = (v3[i] - mu3) * rs3 * gg + bb;
        *(float4*)&O[a] = out;
    }
}

extern "C" void kernel_launch(void* const* d_in, const int* in_sizes, int n_in,
                              void* d_out, int out_size, void* d_ws, size_t ws_size,
                              hipStream_t stream) {
    const float* x     = (const float*)d_in[0];
    const float* ab_w1 = (const float*)d_in[1];
    const float* ab_b1 = (const float*)d_in[2];
    const float* ab_w2 = (const float*)d_in[3];
    const float* ab_b2 = (const float*)d_in[4];
    const float* db_w1 = (const float*)d_in[5];
    const float* db_b1 = (const float*)d_in[6];
    const float* db_w2 = (const float*)d_in[7];
    const float* db_b2 = (const float*)d_in[8];
    const float* ln_g  = (const float*)d_in[9];
    const float* ln_b  = (const float*)d_in[10];

    // workspace (bf16) — keep slot layout (A1/A2 slots unused)
    u16* A1 = (u16*)d_ws;
    u16* D1 = A1 + (size_t)16 * 256 * 4096;
    u16* A2 = D1 + (size_t)16 * 256 * 4096;
    u16* D2 = A2 + (size_t)16 * 256 * 2048;
    u16* A3 = D2 + (size_t)16 * 256 * 2048;
    u16* D3 = A3 + (size_t)16 * 256 * 1024;
    u16* Yb = D3 + (size_t)16 * 256 * 1024;
    u16* Wf = Yb + (size_t)16 * 256 * 8192;
    u16* Wdb1 = Wf;
    u16* Wdb2 = Wf + 65536;
    u16* Wab1 = Wf + 131072;
    u16* Wab2 = Wf + 196608;

    wconv_kernel<<<dim3(32, 4), 256, 0, stream>>>(db_w1, db_w2, ab_w1, ab_w2, Wf);

    // ---- analysis: all 3 DWT levels in one dispatch (A1/A2 never hit HBM) ----
    dwt3_fused_kernel<<<4096, 256, 0, stream>>>(x, D1, D2, D3, A3);

    // ---- all four res-blocks in one dispatch ----
    rb_all_kernel<<<2048, 256, 0, stream>>>(
        D1, D2, D3, A3,
        Wdb1, db_b1, Wdb2, db_b2, Wab1, ab_b1, Wab2, ab_b2);

    // ---- synthesis: all 3 IDWT levels in one dispatch -> Yb ----
    idwt3_fused_kernel<<<4096, 256, 0, stream>>>(A3, D3, D2, D1, Yb);

    // ---- skip + layer norm -> d_out (fp32) ----
    ln_kernel<<<dim3(128, 16), 256, 0, stream>>>(Yb, x, (float*)d_out, ln_g, ln_b);
}

// Round 8
// 387.055 us; speedup vs baseline: 1.5830x; 1.0276x over previous
//
#include <hip/hip_runtime.h>
#include <cstddef>

typedef unsigned short u16;
typedef short short8 __attribute__((ext_vector_type(8)));
typedef float f32x4 __attribute__((ext_vector_type(4)));

// db4 filters (cross-correlation taps, matching lax.conv_general_dilated)
__constant__ float c_dec_lo[8] = {
    -0.010597401785069032f, 0.0328830116668852f, 0.030841381835560764f,
    -0.18703481171888114f, -0.027983769416859854f, 0.6308807679298589f,
    0.7148465705529157f, 0.2303778133088965f};
__constant__ float c_dec_hi[8] = {
    -0.2303778133088965f, 0.7148465705529157f, -0.6308807679298589f,
    -0.027983769416859854f, 0.18703481171888114f, 0.030841381835560764f,
    -0.0328830116668852f, -0.010597401785069032f};
__constant__ float c_rec_lo[8] = {
    0.2303778133088965f, 0.7148465705529157f, 0.6308807679298589f,
    -0.027983769416859854f, -0.18703481171888114f, 0.030841381835560764f,
    0.0328830116668852f, -0.010597401785069032f};
__constant__ float c_rec_hi[8] = {
    -0.010597401785069032f, -0.0328830116668852f, 0.030841381835560764f,
    0.18703481171888114f, -0.027983769416859854f, -0.6308807679298589f,
    0.7148465705529157f, -0.2303778133088965f};

__device__ __forceinline__ float b2f(u16 v) {
    union { unsigned u; float f; } z; z.u = ((unsigned)v) << 16; return z.f;
}
__device__ __forceinline__ float bl(unsigned u) { return b2f((u16)(u & 0xffffu)); }
__device__ __forceinline__ float bh(unsigned u) { return b2f((u16)(u >> 16)); }
__device__ __forceinline__ u16 f2b(float f) {
    union { float f; unsigned u; } z; z.f = f;
    unsigned r = z.u + 0x7fffu + ((z.u >> 16) & 1u);
    return (u16)(r >> 16);
}
__device__ __forceinline__ unsigned pk2(float a, float b) {
    return (unsigned)f2b(a) | ((unsigned)f2b(b) << 16);
}
__device__ __forceinline__ float gelu_tanh(float x) {
    float u = 0.7978845608028654f * (x + 0.044715f * x * x * x);
    float e = __expf(2.f * u);
    float t = 1.f - 2.f / (e + 1.f);
    return 0.5f * x * (1.f + t);
}

// ---------------- weight pre-fragmentation: fp32 [m][k] -> bf16 MFMA A-frag order
__global__ __launch_bounds__(256) void wconv_kernel(
    const float* __restrict__ s0, const float* __restrict__ s1,
    const float* __restrict__ s2, const float* __restrict__ s3,
    u16* __restrict__ dst)
{
    const float* S[4] = {s0, s1, s2, s3};
    const float* src = S[blockIdx.y];
    u16* d = dst + (size_t)blockIdx.y * 65536;
    int gid = blockIdx.x * 256 + threadIdx.x;  // 0..8191
    int lane = gid & 63;
    int kt = (gid >> 6) & 7;
    int mt = gid >> 9;
    int m = mt * 16 + (lane & 15);
    int k = kt * 32 + (lane >> 4) * 8;
    float4 v0 = *(const float4*)&src[m * 256 + k];
    float4 v1 = *(const float4*)&src[m * 256 + k + 4];
    uint4 o;
    o.x = pk2(v0.x, v0.y); o.y = pk2(v0.z, v0.w);
    o.z = pk2(v1.x, v1.y); o.w = pk2(v1.z, v1.w);
    *(uint4*)&d[(size_t)gid * 8] = o;
}

// ---------------- fused 3-level DWT (one block per (b,c) row) ----------------
__global__ __launch_bounds__(256) void dwt3_fused_kernel(
    const float* __restrict__ X, u16* __restrict__ D1, u16* __restrict__ D2,
    u16* __restrict__ D3, u16* __restrict__ A3)
{
    __shared__ __align__(16) float xsh[8200];  // x at [4,8196); later A2 at [4,2052)
    __shared__ __align__(16) float a1h[4104];  // a1 at [4,4100)
    const int tid = threadIdx.x;
    const size_t r = blockIdx.x;               // row = b*256 + c
    const float* xr = X + r * 8192;
#pragma unroll
    for (int i = 0; i < 8; ++i) {
        int j = (tid + i * 256) * 4;
        *(float4*)&xsh[j + 4] = *(const float4*)&xr[j];
    }
    if (tid < 4) {
        xsh[tid] = 0.f; xsh[8196 + tid] = 0.f;
        a1h[tid] = 0.f; a1h[4100 + tid] = 0.f;
    }
    __syncthreads();

    // ---- level 1: 8192 -> 4096 ----
    u16* d1r = D1 + r * 4096;
#pragma unroll
    for (int i = 0; i < 8; ++i) {
        int t0 = 2 * (tid + i * 256);          // even, 0..4094
        const float4* p = (const float4*)&xsh[2 * t0];
        float4 f = p[0], g = p[1], h = p[2];   // xsh[2t0 .. 2t0+11]
        float l0 = c_dec_lo[0]*f.y + c_dec_lo[1]*f.z + c_dec_lo[2]*f.w + c_dec_lo[3]*g.x
                 + c_dec_lo[4]*g.y + c_dec_lo[5]*g.z + c_dec_lo[6]*g.w + c_dec_lo[7]*h.x;
        float h0 = c_dec_hi[0]*f.y + c_dec_hi[1]*f.z + c_dec_hi[2]*f.w + c_dec_hi[3]*g.x
                 + c_dec_hi[4]*g.y + c_dec_hi[5]*g.z + c_dec_hi[6]*g.w + c_dec_hi[7]*h.x;
        float l1 = c_dec_lo[0]*f.w + c_dec_lo[1]*g.x + c_dec_lo[2]*g.y + c_dec_lo[3]*g.z
                 + c_dec_lo[4]*g.w + c_dec_lo[5]*h.x + c_dec_lo[6]*h.y + c_dec_lo[7]*h.z;
        float h1 = c_dec_hi[0]*f.w + c_dec_hi[1]*g.x + c_dec_hi[2]*g.y + c_dec_hi[3]*g.z
                 + c_dec_hi[4]*g.w + c_dec_hi[5]*h.x + c_dec_hi[6]*h.y + c_dec_hi[7]*h.z;
        *(float2*)&a1h[t0 + 4] = make_float2(l0, l1);
        *(unsigned*)&d1r[t0] = pk2(h0, h1);
    }
    __syncthreads();

    // ---- level 2: 4096 -> 2048 (lo -> A2 overlay on xsh) ----
    u16* d2r = D2 + r * 2048;
    if (tid < 4) xsh[2052 + tid] = 0.f;        // A2 upper halo (lower already 0)
#pragma unroll
    for (int i = 0; i < 4; ++i) {
        int t0 = 2 * (tid + i * 256);          // 0..2046
        const float4* p = (const float4*)&a1h[2 * t0];
        float4 f = p[0], g = p[1], h = p[2];
        float l0 = c_dec_lo[0]*f.y + c_dec_lo[1]*f.z + c_dec_lo[2]*f.w + c_dec_lo[3]*g.x
                 + c_dec_lo[4]*g.y + c_dec_lo[5]*g.z + c_dec_lo[6]*g.w + c_dec_lo[7]*h.x;
        float h0 = c_dec_hi[0]*f.y + c_dec_hi[1]*f.z + c_dec_hi[2]*f.w + c_dec_hi[3]*g.x
                 + c_dec_hi[4]*g.y + c_dec_hi[5]*g.z + c_dec_hi[6]*g.w + c_dec_hi[7]*h.x;
        float l1 = c_dec_lo[0]*f.w + c_dec_lo[1]*g.x + c_dec_lo[2]*g.y + c_dec_lo[3]*g.z
                 + c_dec_lo[4]*g.w + c_dec_lo[5]*h.x + c_dec_lo[6]*h.y + c_dec_lo[7]*h.z;
        float h1 = c_dec_hi[0]*f.w + c_dec_hi[1]*g.x + c_dec_hi[2]*g.y + c_dec_hi[3]*g.z
                 + c_dec_hi[4]*g.w + c_dec_hi[5]*h.x + c_dec_hi[6]*h.y + c_dec_hi[7]*h.z;
        *(float2*)&xsh[t0 + 4] = make_float2(l0, l1);
        *(unsigned*)&d2r[t0] = pk2(h0, h1);
    }
    __syncthreads();

    // ---- level 3: 2048 -> 1024 ----
    u16* d3r = D3 + r * 1024;
    u16* a3r = A3 + r * 1024;
#pragma unroll
    for (int i = 0; i < 2; ++i) {
        int t0 = 2 * (tid + i * 256);          // 0..1022
        const float4* p = (const float4*)&xsh[2 * t0];
        float4 f = p[0], g = p[1], h = p[2];
        float l0 = c_dec_lo[0]*f.y + c_dec_lo[1]*f.z + c_dec_lo[2]*f.w + c_dec_lo[3]*g.x
                 + c_dec_lo[4]*g.y + c_dec_lo[5]*g.z + c_dec_lo[6]*g.w + c_dec_lo[7]*h.x;
        float h0 = c_dec_hi[0]*f.y + c_dec_hi[1]*f.z + c_dec_hi[2]*f.w + c_dec_hi[3]*g.x
                 + c_dec_hi[4]*g.y + c_dec_hi[5]*g.z + c_dec_hi[6]*g.w + c_dec_hi[7]*h.x;
        float l1 = c_dec_lo[0]*f.w + c_dec_lo[1]*g.x + c_dec_lo[2]*g.y + c_dec_lo[3]*g.z
                 + c_dec_lo[4]*g.w + c_dec_lo[5]*h.x + c_dec_lo[6]*h.y + c_dec_lo[7]*h.z;
        float h1 = c_dec_hi[0]*f.w + c_dec_hi[1]*g.x + c_dec_hi[2]*g.y + c_dec_hi[3]*g.z
                 + c_dec_hi[4]*g.w + c_dec_hi[5]*h.x + c_dec_hi[6]*h.y + c_dec_hi[7]*h.z;
        *(unsigned*)&a3r[t0] = pk2(l0, l1);
        *(unsigned*)&d3r[t0] = pk2(h0, h1);
    }
}

// ---------------- fused 3-level IDWT (one block per (b,c) row) ----------------
__global__ __launch_bounds__(256) void idwt3_fused_kernel(
    const u16* __restrict__ A3, const u16* __restrict__ D3,
    const u16* __restrict__ D2, const u16* __restrict__ D1,
    u16* __restrict__ Y)
{
    __shared__ __align__(16) u16 a3h[1040], d3h[1040], d2h[2064], d1h[4112];
    __shared__ __align__(16) float y2h[2056], y4h[4104];
    const int tid = threadIdx.x;
    const size_t r = blockIdx.x;

    {
        const uint4* a3r = (const uint4*)(A3 + r * 1024);   // 128 uint4
        const uint4* d3r = (const uint4*)(D3 + r * 1024);
        const uint4* d2r = (const uint4*)(D2 + r * 2048);   // 256
        const uint4* d1r = (const uint4*)(D1 + r * 4096);   // 512
        if (tid < 128) {
            *(uint4*)&a3h[8 * tid + 8] = a3r[tid];
        } else {
            int j = tid - 128;
            *(uint4*)&d3h[8 * j + 8] = d3r[j];
        }
        *(uint4*)&d2h[8 * tid + 8] = d2r[tid];
        *(uint4*)&d1h[8 * tid + 8] = d1r[tid];
        *(uint4*)&d1h[8 * (tid + 256) + 8] = d1r[tid + 256];
        if (tid < 8) {
            a3h[tid] = 0; a3h[1032 + tid] = 0;
            d3h[tid] = 0; d3h[1032 + tid] = 0;
            d2h[tid] = 0; d2h[2056 + tid] = 0;
            d1h[tid] = 0; d1h[4104 + tid] = 0;
        }
        if (tid < 4) {
            y2h[tid] = 0.f; y2h[2052 + tid] = 0.f;
            y4h[tid] = 0.f; y4h[4100 + tid] = 0.f;
        }
    }
    __syncthreads();

    const float rl0 = c_rec_lo[0], rl1 = c_rec_lo[1], rl2 = c_rec_lo[2],
                rl3 = c_rec_lo[3], rl4 = c_rec_lo[4], rl5 = c_rec_lo[5],
                rl6 = c_rec_lo[6], rl7 = c_rec_lo[7];
    const float rh0 = c_rec_hi[0], rh1 = c_rec_hi[1], rh2 = c_rec_hi[2],
                rh3 = c_rec_hi[3], rh4 = c_rec_hi[4], rh5 = c_rec_hi[5],
                rh6 = c_rec_hi[6], rh7 = c_rec_hi[7];

    // ---- stage 1: (a3,d3)@1024 -> y2h ----
#pragma unroll
    for (int i = 0; i < 2; ++i) {
        int s = 2 * (tid + i * 256);           // even, 0..1022
        unsigned ua0 = *(const unsigned*)&a3h[s + 6];
        unsigned ua1 = *(const unsigned*)&a3h[s + 8];
        unsigned ua2 = *(const unsigned*)&a3h[s + 10];
        unsigned ud0 = *(const unsigned*)&d3h[s + 6];
        unsigned ud1 = *(const unsigned*)&d3h[s + 8];
        unsigned ud2 = *(const unsigned*)&d3h[s + 10];
        float am2 = bl(ua0), am1 = bh(ua0), a0 = bl(ua1), a1 = bh(ua1),
              a2 = bl(ua2), a3 = bh(ua2);
        float dm2 = bl(ud0), dm1 = bh(ud0), d0 = bl(ud1), d1 = bh(ud1),
              d2 = bl(ud2), d3 = bh(ud2);
        float4 o;
        o.x = rl7*am2 + rl5*am1 + rl3*a0 + rl1*a1 + rh7*dm2 + rh5*dm1 + rh3*d0 + rh1*d1;
        o.y = rl6*am1 + rl4*a0 + rl2*a1 + rl0*a2 + rh6*dm1 + rh4*d0 + rh2*d1 + rh0*d2;
        o.z = rl7*am1 + rl5*a0 + rl3*a1 + rl1*a2 + rh7*dm1 + rh5*d0 + rh3*d1 + rh1*d2;
        o.w = rl6*a0 + rl4*a1 + rl2*a2 + rl0*a3 + rh6*d0 + rh4*d1 + rh2*d2 + rh0*d3;
        *(float4*)&y2h[2 * s + 4] = o;
    }
    __syncthreads();

    // ---- stage 2: (y2h, d2)@2048 -> y4h ----
#pragma unroll
    for (int i = 0; i < 4; ++i) {
        int s = 2 * (tid + i * 256);           // 0..2046
        const float2* p = (const float2*)&y2h[s + 2];
        float2 fa = p[0], fb = p[1], fc = p[2];
        float am2 = fa.x, am1 = fa.y, a0 = fb.x, a1 = fb.y, a2 = fc.x, a3 = fc.y;
        unsigned ud0 = *(const unsigned*)&d2h[s + 6];
        unsigned ud1 = *(const unsigned*)&d2h[s + 8];
        unsigned ud2 = *(const unsigned*)&d2h[s + 10];
        float dm2 = bl(ud0), dm1 = bh(ud0), d0 = bl(ud1), d1 = bh(ud1),
              d2 = bl(ud2), d3 = bh(ud2);
        float4 o;
        o.x = rl7*am2 + rl5*am1 + rl3*a0 + rl1*a1 + rh7*dm2 + rh5*dm1 + rh3*d0 + rh1*d1;
        o.y = rl6*am1 + rl4*a0 + rl2*a1 + rl0*a2 + rh6*dm1 + rh4*d0 + rh2*d1 + rh0*d2;
        o.z = rl7*am1 + rl5*a0 + rl3*a1 + rl1*a2 + rh7*dm1 + rh5*d0 + rh3*d1 + rh1*d2;
        o.w = rl6*a0 + rl4*a1 + rl2*a2 + rl0*a3 + rh6*d0 + rh4*d1 + rh2*d2 + rh0*d3;
        *(float4*)&y4h[2 * s + 4] = o;
    }
    __syncthreads();

    // ---- stage 3: (y4h, d1)@4096 -> Y row ----
    u16* yr = Y + r * 8192;
#pragma unroll
    for (int i = 0; i < 8; ++i) {
        int s = 2 * (tid + i * 256);           // 0..4094
        const float2* p = (const float2*)&y4h[s + 2];
        float2 fa = p[0], fb = p[1], fc = p[2];
        float am2 = fa.x, am1 = fa.y, a0 = fb.x, a1 = fb.y, a2 = fc.x, a3 = fc.y;
        unsigned ud0 = *(const unsigned*)&d1h[s + 6];
        unsigned ud1 = *(const unsigned*)&d1h[s + 8];
        unsigned ud2 = *(const unsigned*)&d1h[s + 10];
        float dm2 = bl(ud0), dm1 = bh(ud0), d0 = bl(ud1), d1 = bh(ud1),
              d2 = bl(ud2), d3 = bh(ud2);
        float ye0 = rl7*am2 + rl5*am1 + rl3*a0 + rl1*a1 + rh7*dm2 + rh5*dm1 + rh3*d0 + rh1*d1;
        float yo0 = rl6*am1 + rl4*a0 + rl2*a1 + rl0*a2 + rh6*dm1 + rh4*d0 + rh2*d1 + rh0*d2;
        float ye1 = rl7*am1 + rl5*a0 + rl3*a1 + rl1*a2 + rh7*dm1 + rh5*d0 + rh3*d1 + rh1*d2;
        float yo1 = rl6*a0 + rl4*a1 + rl2*a2 + rl0*a3 + rh6*d0 + rh4*d1 + rh2*d2 + rh0*d3;
        uint2 o; o.x = pk2(ye0, yo0); o.y = pk2(ye1, yo1);
        *(uint2*)&yr[2 * s] = o;
    }
}

// ---------------- fused ResConv1dBlock (bf16 MFMA, 512 threads / 8 waves) ----
// Each wave owns 32 output rows (acc[2][4]); same 64-col tile, same LDS as the
// 4-wave version -> 2 blocks/CU but 16 waves/CU (was 8): VALU/MFMA co-schedule.
#define KPAD 264

__device__ __forceinline__ void gemm_phase8(
    const u16* __restrict__ Wf, const u16* __restrict__ Bs,
    int lane, int w, int fl, int fq, f32x4 acc[2][4])
{
    const u16* wb = Wf + (size_t)(2 * w) * 4096 + (size_t)lane * 8;
    short8 a[2], an[2];
#pragma unroll
    for (int i = 0; i < 2; ++i)
        a[i] = *(const short8*)(wb + i * 4096);
#pragma unroll
    for (int kt = 0; kt < 8; ++kt) {
        if (kt < 7) {
#pragma unroll
            for (int i = 0; i < 2; ++i)
                an[i] = *(const short8*)(wb + i * 4096 + (kt + 1) * 512);
        }
        short8 bf[4];
#pragma unroll
        for (int nt = 0; nt < 4; ++nt)
            bf[nt] = *(const short8*)&Bs[(nt * 16 + fl) * KPAD + kt * 32 + fq * 8];
#pragma unroll
        for (int i = 0; i < 2; ++i)
#pragma unroll
            for (int nt = 0; nt < 4; ++nt)
                acc[i][nt] = __builtin_amdgcn_mfma_f32_16x16x32_bf16(
                    a[i], bf[nt], acc[i][nt], 0, 0, 0);
#pragma unroll
        for (int i = 0; i < 2; ++i) a[i] = an[i];
    }
}

__device__ __forceinline__ void rb_body(
    const u16* __restrict__ Xg, u16* __restrict__ Outg,
    const u16* __restrict__ W1f, const float* __restrict__ b1,
    const u16* __restrict__ W2f, const float* __restrict__ b2,
    int L, int n0, int batch)
{
    __shared__ u16 Xs[64 * KPAD];
    __shared__ u16 Hs[64 * KPAD];
    const int tid = threadIdx.x;      // 0..511
    const int lane = tid & 63;
    const int w = tid >> 6;           // wave 0..7 -> rows 32w..32w+31
    const int fl = lane & 15;
    const int fq = lane >> 4;
    const size_t bbase = (size_t)batch * 256 * (size_t)L;

    // ---- stage X: global [k][n] bf16 -> Xs[n][k] (4x4 register transpose) ----
    {
        const int nq = tid & 15;
        const int kq = tid >> 4;  // 0..31
        const u16* src = Xg + bbase + n0 + 4 * nq;
#pragma unroll
        for (int p = 0; p < 2; ++p) {
            int kb = p * 128 + kq * 4;
            uint2 r0 = *(const uint2*)(src + (size_t)(kb + 0) * L);
            uint2 r1 = *(const uint2*)(src + (size_t)(kb + 1) * L);
            uint2 r2 = *(const uint2*)(src + (size_t)(kb + 2) * L);
            uint2 r3 = *(const uint2*)(src + (size_t)(kb + 3) * L);
#pragma unroll
            for (int j = 0; j < 4; ++j) {
                unsigned e0 = ((j < 2 ? r0.x : r0.y) >> ((j & 1) * 16)) & 0xffffu;
                unsigned e1 = ((j < 2 ? r1.x : r1.y) >> ((j & 1) * 16)) & 0xffffu;
                unsigned e2 = ((j < 2 ? r2.x : r2.y) >> ((j & 1) * 16)) & 0xffffu;
                unsigned e3 = ((j < 2 ? r3.x : r3.y) >> ((j & 1) * 16)) & 0xffffu;
                uint2 o; o.x = e0 | (e1 << 16); o.y = e2 | (e3 << 16);
                *(uint2*)&Xs[(4 * nq + j) * KPAD + kb] = o;
            }
        }
    }
    __syncthreads();

    // ---- GEMM1: H = gelu(W1 @ X + b1) ----
    f32x4 acc[2][4];
#pragma unroll
    for (int i = 0; i < 2; ++i)
#pragma unroll
        for (int nt = 0; nt < 4; ++nt) acc[i][nt] = (f32x4){0.f, 0.f, 0.f, 0.f};
    gemm_phase8(W1f, Xs, lane, w, fl, fq, acc);
#pragma unroll
    for (int i = 0; i < 2; ++i) {
        const int m0 = 32 * w + i * 16 + fq * 4;
        float4 bv = *(const float4*)&b1[m0];
#pragma unroll
        for (int nt = 0; nt < 4; ++nt) {
            float v0 = gelu_tanh(acc[i][nt][0] + bv.x);
            float v1 = gelu_tanh(acc[i][nt][1] + bv.y);
            float v2 = gelu_tanh(acc[i][nt][2] + bv.z);
            float v3 = gelu_tanh(acc[i][nt][3] + bv.w);
            uint2 o; o.x = pk2(v0, v1); o.y = pk2(v2, v3);
            *(uint2*)&Hs[(nt * 16 + fl) * KPAD + m0] = o;
        }
    }
    __syncthreads();

    // ---- GEMM2: Out = X0 + W2 @ H + b2 ----
#pragma unroll
    for (int i = 0; i < 2; ++i)
#pragma unroll
        for (int nt = 0; nt < 4; ++nt) acc[i][nt] = (f32x4){0.f, 0.f, 0.f, 0.f};
    gemm_phase8(W2f, Hs, lane, w, fl, fq, acc);

    uint2 outv[2][4];
#pragma unroll
    for (int i = 0; i < 2; ++i) {
        const int m0 = 32 * w + i * 16 + fq * 4;
        float4 bv = *(const float4*)&b2[m0];
#pragma unroll
        for (int nt = 0; nt < 4; ++nt) {
            const int n = nt * 16 + fl;
            uint2 x0 = *(const uint2*)&Xs[n * KPAD + m0];
            float v0 = acc[i][nt][0] + bv.x + b2f((u16)(x0.x & 0xffffu));
            float v1 = acc[i][nt][1] + bv.y + b2f((u16)(x0.x >> 16));
            float v2 = acc[i][nt][2] + bv.z + b2f((u16)(x0.y & 0xffffu));
            float v3 = acc[i][nt][3] + bv.w + b2f((u16)(x0.y >> 16));
            outv[i][nt].x = pk2(v0, v1);
            outv[i][nt].y = pk2(v2, v3);
        }
    }
    __syncthreads();  // all waves finished reading Hs
#pragma unroll
    for (int i = 0; i < 2; ++i) {
        const int m0 = 32 * w + i * 16 + fq * 4;
#pragma unroll
        for (int nt = 0; nt < 4; ++nt)
            *(uint2*)&Hs[(nt * 16 + fl) * KPAD + m0] = outv[i][nt];
    }
    __syncthreads();

    // ---- coalesced store: Hs[n][m] -> Out[m][n] ----
    {
        const int n = tid & 63;
        const int mB = (tid >> 6) * 32;
        u16* dst = Outg + bbase + n0 + n;
#pragma unroll
        for (int mi = 0; mi < 8; ++mi) {
            int m = mB + mi * 4;
            uint2 v = *(const uint2*)&Hs[n * KPAD + m];
            dst[(size_t)(m + 0) * L] = (u16)(v.x & 0xffffu);
            dst[(size_t)(m + 1) * L] = (u16)(v.x >> 16);
            dst[(size_t)(m + 2) * L] = (u16)(v.y & 0xffffu);
            dst[(size_t)(m + 3) * L] = (u16)(v.y >> 16);
        }
    }
}

// All four res-blocks in ONE dispatch (grid 2048, 512 threads):
//   [0,1024):    D1, L=4096 (64 col-blocks x 16 batches)
//   [1024,1536): D2, L=2048 (32 x 16)
//   [1536,1792): D3, L=1024 (16 x 16)
//   [1792,2048): A3, L=1024 (16 x 16, ab weights)
__global__ __launch_bounds__(512, 4) void rb_all_kernel(
    u16* __restrict__ D1, u16* __restrict__ D2, u16* __restrict__ D3,
    u16* __restrict__ A3,
    const u16* __restrict__ Wdb1, const float* __restrict__ db_b1,
    const u16* __restrict__ Wdb2, const float* __restrict__ db_b2,
    const u16* __restrict__ Wab1, const float* __restrict__ ab_b1,
    const u16* __restrict__ Wab2, const float* __restrict__ ab_b2)
{
    const int bx = blockIdx.x;
    u16* Xg; const u16* W1; const float* B1; const u16* W2; const float* B2;
    int L, n0, batch;
    if (bx < 1024) {
        L = 4096; n0 = (bx & 63) * 64; batch = bx >> 6;
        Xg = D1; W1 = Wdb1; B1 = db_b1; W2 = Wdb2; B2 = db_b2;
    } else if (bx < 1536) {
        int lo = bx - 1024;
        L = 2048; n0 = (lo & 31) * 64; batch = lo >> 5;
        Xg = D2; W1 = Wdb1; B1 = db_b1; W2 = Wdb2; B2 = db_b2;
    } else if (bx < 1792) {
        int lo = bx - 1536;
        L = 1024; n0 = (lo & 15) * 64; batch = lo >> 4;
        Xg = D3; W1 = Wdb1; B1 = db_b1; W2 = Wdb2; B2 = db_b2;
    } else {
        int lo = bx - 1792;
        L = 1024; n0 = (lo & 15) * 64; batch = lo >> 4;
        Xg = A3; W1 = Wab1; B1 = ab_b1; W2 = Wab2; B2 = ab_b2;
    }
    rb_body(Xg, Xg, W1, B1, W2, B2, L, n0, batch);
}

// ---------------- LayerNorm over channels: out = LN(y + x) ----------------
// 64 cols/block, 4 cols x 16 channels per thread (ushort4/float4 loads).
__global__ __launch_bounds__(256) void ln_kernel(
    const u16* __restrict__ Yb, const float* __restrict__ X,
    float* __restrict__ O, const float* __restrict__ g, const float* __restrict__ be)
{
    __shared__ float ps[4][16][8];
    __shared__ float smu[64], srs[64];
    const int tid = threadIdx.x;
    const int lp = tid & 15;   // column quad: cols 4*lp .. 4*lp+3
    const int cg = tid >> 4;   // channel group 0..15 (16 channels each)
    const int c0 = cg * 16;
    const size_t base = (size_t)blockIdx.y * 256 * 8192 +
                        (size_t)blockIdx.x * 64 + 4 * lp;
    float v0[16], v1[16], v2[16], v3[16];
    float s0 = 0.f, s1 = 0.f, s2 = 0.f, s3 = 0.f;
    float q0 = 0.f, q1 = 0.f, q2 = 0.f, q3 = 0.f;
#pragma unroll
    for (int i = 0; i < 16; ++i) {
        size_t a = base + (size_t)(c0 + i) * 8192;
        ushort4 y4 = *(const ushort4*)&Yb[a];
        float4 x4 = *(const float4*)&X[a];
        float va = b2f(y4.x) + x4.x;
        float vb = b2f(y4.y) + x4.y;
        float vc = b2f(y4.z) + x4.z;
        float vd = b2f(y4.w) + x4.w;
        v0[i] = va; v1[i] = vb; v2[i] = vc; v3[i] = vd;
        s0 += va; q0 += va * va;
        s1 += vb; q1 += vb * vb;
        s2 += vc; q2 += vc * vc;
        s3 += vd; q3 += vd * vd;
    }
    s0 += __shfl_xor(s0, 16); q0 += __shfl_xor(q0, 16);
    s1 += __shfl_xor(s1, 16); q1 += __shfl_xor(q1, 16);
    s2 += __shfl_xor(s2, 16); q2 += __shfl_xor(q2, 16);
    s3 += __shfl_xor(s3, 16); q3 += __shfl_xor(q3, 16);
    s0 += __shfl_xor(s0, 32); q0 += __shfl_xor(q0, 32);
    s1 += __shfl_xor(s1, 32); q1 += __shfl_xor(q1, 32);
    s2 += __shfl_xor(s2, 32); q2 += __shfl_xor(q2, 32);
    s3 += __shfl_xor(s3, 32); q3 += __shfl_xor(q3, 32);
    const int w = tid >> 6;
    if ((tid & 63) < 16) {
        ps[w][lp][0] = s0; ps[w][lp][1] = q0;
        ps[w][lp][2] = s1; ps[w][lp][3] = q1;
        ps[w][lp][4] = s2; ps[w][lp][5] = q2;
        ps[w][lp][6] = s3; ps[w][lp][7] = q3;
    }
    __syncthreads();
    if (tid < 16) {
#pragma unroll
        for (int j = 0; j < 4; ++j) {
            float S = 0.f, Q = 0.f;
#pragma unroll
            for (int i = 0; i < 4; ++i) {
                S += ps[i][tid][2 * j];
                Q += ps[i][tid][2 * j + 1];
            }
            float m = S * (1.f / 256.f);
            smu[4 * tid + j] = m;
            srs[4 * tid + j] = rsqrtf(Q * (1.f / 256.f) - m * m + 1e-5f);
        }
    }
    __syncthreads();
    const float mu0 = smu[4 * lp + 0], mu1 = smu[4 * lp + 1],
                mu2 = smu[4 * lp + 2], mu3 = smu[4 * lp + 3];
    const float rs0 = srs[4 * lp + 0], rs1 = srs[4 * lp + 1],
                rs2 = srs[4 * lp + 2], rs3 = srs[4 * lp + 3];
#pragma unroll
    for (int i = 0; i < 16; ++i) {
        size_t a = base + (size_t)(c0 + i) * 8192;
        float gg = g[c0 + i], bb = be[c0 + i];
        float4 out;
        out.x = (v0[i] - mu0) * rs0 * gg + bb;
        out.y = (v1[i] - mu1) * rs1 * gg + bb;
        out.z = (v2[i] - mu2) * rs2 * gg + bb;
        out.w = (v3[i] - mu3) * rs3 * gg + bb;
        *(float4*)&O[a] = out;
    }
}

extern "C" void kernel_launch(void* const* d_in, const int* in_sizes, int n_in,
                              void* d_out, int out_size, void* d_ws, size_t ws_size,
                              hipStream_t stream) {
    const float* x     = (const float*)d_in[0];
    const float* ab_w1 = (const float*)d_in[1];
    const float* ab_b1 = (const float*)d_in[2];
    const float* ab_w2 = (const float*)d_in[3];
    const float* ab_b2 = (const float*)d_in[4];
    const float* db_w1 = (const float*)d_in[5];
    const float* db_b1 = (const float*)d_in[6];
    const float* db_w2 = (const float*)d_in[7];
    const float* db_b2 = (const float*)d_in[8];
    const float* ln_g  = (const float*)d_in[9];
    const float* ln_b  = (const float*)d_in[10];

    // workspace (bf16) — keep slot layout (A1/A2 slots unused)
    u16* A1 = (u16*)d_ws;
    u16* D1 = A1 + (size_t)16 * 256 * 4096;
    u16* A2 = D1 + (size_t)16 * 256 * 4096;
    u16* D2 = A2 + (size_t)16 * 256 * 2048;
    u16* A3 = D2 + (size_t)16 * 256 * 2048;
    u16* D3 = A3 + (size_t)16 * 256 * 1024;
    u16* Yb = D3 + (size_t)16 * 256 * 1024;
    u16* Wf = Yb + (size_t)16 * 256 * 8192;
    u16* Wdb1 = Wf;
    u16* Wdb2 = Wf + 65536;
    u16* Wab1 = Wf + 131072;
    u16* Wab2 = Wf + 196608;

    wconv_kernel<<<dim3(32, 4), 256, 0, stream>>>(db_w1, db_w2, ab_w1, ab_w2, Wf);

    // ---- analysis: all 3 DWT levels in one dispatch (A1/A2 never hit HBM) ----
    dwt3_fused_kernel<<<4096, 256, 0, stream>>>(x, D1, D2, D3, A3);

    // ---- all four res-blocks in one dispatch (8 waves/block) ----
    rb_all_kernel<<<2048, 512, 0, stream>>>(
        D1, D2, D3, A3,
        Wdb1, db_b1, Wdb2, db_b2, Wab1, ab_b1, Wab2, ab_b2);

    // ---- synthesis: all 3 IDWT levels in one dispatch -> Yb ----
    idwt3_fused_kernel<<<4096, 256, 0, stream>>>(A3, D3, D2, D1, Yb);

    // ---- skip + layer norm -> d_out (fp32) ----
    ln_kernel<<<dim3(128, 16), 256, 0, stream>>>(Yb, x, (float*)d_out, ln_g, ln_b);
}